// Round 2
// baseline (78916.345 us; speedup 1.0000x reference)
//
#include <hip/hip_runtime.h>
#include <math.h>

#define LRELU(x) ((x) > 0.0f ? (x) : 0.01f * (x))

__device__ __forceinline__ unsigned fenc(float f) {
    unsigned u = __float_as_uint(f);
    return (u & 0x80000000u) ? ~u : (u | 0x80000000u);
}
__device__ __forceinline__ float fdec(unsigned u) {
    return __uint_as_float((u & 0x80000000u) ? (u & 0x7FFFFFFFu) : ~u);
}
__device__ __forceinline__ unsigned short f2bf(float f) {
    unsigned u = __float_as_uint(f);
    u += 0x7FFFu + ((u >> 16) & 1u);
    return (unsigned short)(u >> 16);
}
__device__ __forceinline__ float bf2f(unsigned short b) {
    return __uint_as_float(((unsigned)b) << 16);
}

// ------------ GEMM: C[M,256](bf16) = A[M,128] @ W[256,128]^T ------------
// tile 64(M) x 64(N), BK=32, 256 threads, 4x4 microtile
__global__ __launch_bounds__(256) void gemm_f128_bf16(
    const float* __restrict__ A, const float* __restrict__ W,
    unsigned short* __restrict__ C, int M)
{
    __shared__ float As[32][65];
    __shared__ float Bs[32][65];
    const int row0 = blockIdx.x * 64;
    const int col0 = blockIdx.y * 64;
    const int tid = threadIdx.x;
    const int tx = tid & 15, ty = tid >> 4;
    const int tm0 = ty * 4, tn0 = tx * 4;
    float acc[4][4] = {};
#pragma unroll
    for (int k0 = 0; k0 < 128; k0 += 32) {
        for (int i = tid; i < 64 * 8; i += 256) {
            int m = i >> 3, k4 = (i & 7) * 4;
            int r = row0 + m;
            float4 v = make_float4(0.f, 0.f, 0.f, 0.f);
            if (r < M) v = *(const float4*)&A[(size_t)r * 128 + k0 + k4];
            As[k4][m] = v.x; As[k4 + 1][m] = v.y; As[k4 + 2][m] = v.z; As[k4 + 3][m] = v.w;
        }
        for (int i = tid; i < 64 * 8; i += 256) {
            int n = i >> 3, k4 = (i & 7) * 4;
            float4 v = *(const float4*)&W[(size_t)(col0 + n) * 128 + k0 + k4];
            Bs[k4][n] = v.x; Bs[k4 + 1][n] = v.y; Bs[k4 + 2][n] = v.z; Bs[k4 + 3][n] = v.w;
        }
        __syncthreads();
#pragma unroll
        for (int kk = 0; kk < 32; ++kk) {
            float av[4], bv[4];
#pragma unroll
            for (int i = 0; i < 4; ++i) av[i] = As[kk][tm0 + i];
#pragma unroll
            for (int j = 0; j < 4; ++j) bv[j] = Bs[kk][tn0 + j];
#pragma unroll
            for (int i = 0; i < 4; ++i)
#pragma unroll
                for (int j = 0; j < 4; ++j) acc[i][j] += av[i] * bv[j];
        }
        __syncthreads();
    }
#pragma unroll
    for (int i = 0; i < 4; ++i) {
        int r = row0 + tm0 + i;
        if (r < M) {
            ushort4 p;
            p.x = f2bf(acc[i][0]); p.y = f2bf(acc[i][1]);
            p.z = f2bf(acc[i][2]); p.w = f2bf(acc[i][3]);
            *(ushort4*)&C[(size_t)r * 256 + col0 + tn0] = p;
        }
    }
}

// ------ fused fij GEMM + attention score (no fij materialization) ------
// blockIdx.y = head (64 cols); epilogue: score = sum_col lrelu(fij+ni[s]+nj[d]+b)*attn
__global__ __launch_bounds__(256) void gemm_score(
    const float* __restrict__ A, const float* __restrict__ W,
    const unsigned short* __restrict__ fni, const unsigned short* __restrict__ fnj,
    const float* __restrict__ bias, const float* __restrict__ attn,
    const int* __restrict__ src, const int* __restrict__ dst,
    float* __restrict__ ebuf, unsigned* __restrict__ smax, int M)
{
    __shared__ float smem[64 * 65];   // As[32][65]+Bs[32][65] then Csh[64][65]
    float* As = smem;
    float* Bs = smem + 32 * 65;
    const int head = blockIdx.y;
    const int col0 = head * 64;
    const int row0 = blockIdx.x * 64;
    const int tid = threadIdx.x;
    const int tx = tid & 15, ty = tid >> 4;
    const int tm0 = ty * 4, tn0 = tx * 4;
    float acc[4][4] = {};
#pragma unroll
    for (int k0 = 0; k0 < 128; k0 += 32) {
        for (int i = tid; i < 64 * 8; i += 256) {
            int m = i >> 3, k4 = (i & 7) * 4;
            int r = row0 + m;
            float4 v = make_float4(0.f, 0.f, 0.f, 0.f);
            if (r < M) v = *(const float4*)&A[(size_t)r * 128 + k0 + k4];
            As[k4 * 65 + m] = v.x; As[(k4 + 1) * 65 + m] = v.y;
            As[(k4 + 2) * 65 + m] = v.z; As[(k4 + 3) * 65 + m] = v.w;
        }
        for (int i = tid; i < 64 * 8; i += 256) {
            int n = i >> 3, k4 = (i & 7) * 4;
            float4 v = *(const float4*)&W[(size_t)(col0 + n) * 128 + k0 + k4];
            Bs[k4 * 65 + n] = v.x; Bs[(k4 + 1) * 65 + n] = v.y;
            Bs[(k4 + 2) * 65 + n] = v.z; Bs[(k4 + 3) * 65 + n] = v.w;
        }
        __syncthreads();
#pragma unroll
        for (int kk = 0; kk < 32; ++kk) {
            float av[4], bv[4];
#pragma unroll
            for (int i = 0; i < 4; ++i) av[i] = As[kk * 65 + tm0 + i];
#pragma unroll
            for (int j = 0; j < 4; ++j) bv[j] = Bs[kk * 65 + tn0 + j];
#pragma unroll
            for (int i = 0; i < 4; ++i)
#pragma unroll
                for (int j = 0; j < 4; ++j) acc[i][j] += av[i] * bv[j];
        }
        __syncthreads();
    }
    // stash tile in LDS (reuses As/Bs space — all reads done)
    float* Csh = smem;  // [64][65]
#pragma unroll
    for (int i = 0; i < 4; ++i)
#pragma unroll
        for (int j = 0; j < 4; ++j)
            Csh[(tm0 + i) * 65 + tn0 + j] = acc[i][j];
    __syncthreads();
    const int lane = tid & 63, wv = tid >> 6;
    for (int rr = 0; rr < 16; ++rr) {
        int row = wv * 16 + rr;
        int r = row0 + row;
        if (r >= M) break;
        int s = src[r], d = dst[r];
        float v = Csh[row * 65 + lane]
                + bf2f(fni[(size_t)s * 256 + col0 + lane])
                + bf2f(fnj[(size_t)d * 256 + col0 + lane])
                + bias[col0 + lane];
        v = LRELU(v) * attn[col0 + lane];
#pragma unroll
        for (int off = 32; off; off >>= 1) v += __shfl_down(v, off, 64);
        if (lane == 0) {
            ebuf[(size_t)r * 4 + head] = v;
            atomicMax(&smax[(size_t)d * 4 + head], fenc(v));
        }
    }
}

// ---------------- softmax pass 2: exp(e-max), atomic denom ----------------
__global__ __launch_bounds__(256) void edge_exp(
    float* __restrict__ ebuf, const unsigned* __restrict__ smax,
    float* __restrict__ sden, const int* __restrict__ dst, int nE)
{
    int i = blockIdx.x * 256 + threadIdx.x;
    if (i >= nE * 4) return;
    int e = i >> 2, h = i & 3;
    int d = dst[e];
    float m = fdec(smax[(size_t)d * 4 + h]);
    float ex = expf(ebuf[i] - m);
    ebuf[i] = ex;
    atomicAdd(&sden[(size_t)d * 4 + h], ex);
}

// ---------------- mean-aggregate x_feats onto lg_dst ----------------
__global__ __launch_bounds__(256) void agg_x(
    const float* __restrict__ x, const int* __restrict__ dst,
    float* __restrict__ agg, float* __restrict__ cnt, int nE2)
{
    const int k = threadIdx.x & 127;
    const int e = blockIdx.x * 2 + (threadIdx.x >> 7);
    if (e >= nE2) return;
    const int d = dst[e];
    atomicAdd(&agg[(size_t)d * 128 + k], x[(size_t)e * 128 + k]);
    if (k == 0) atomicAdd(&cnt[d], 1.0f);
}

__global__ __launch_bounds__(256) void agg_div(
    float* __restrict__ agg, const float* __restrict__ cnt, long long n)
{
    long long i = (long long)blockIdx.x * 256 + threadIdx.x;
    if (i >= n) return;
    agg[i] /= fmaxf(cnt[i >> 7], 1.0f);
}

// -------- h1 GEMM: A = [m_feats | agg] (K=256), +bias, bf16 out --------
__global__ __launch_bounds__(256) void gemm_h1_bf16(
    const float* __restrict__ mfe, const float* __restrict__ agg,
    const float* __restrict__ W, const float* __restrict__ bias,
    unsigned short* __restrict__ C, int M)
{
    __shared__ float As[32][65];
    __shared__ float Bs[32][65];
    const int row0 = blockIdx.x * 64;
    const int col0 = blockIdx.y * 64;
    const int tid = threadIdx.x;
    const int tx = tid & 15, ty = tid >> 4;
    const int tm0 = ty * 4, tn0 = tx * 4;
    float acc[4][4] = {};
#pragma unroll
    for (int k0 = 0; k0 < 256; k0 += 32) {
        for (int i = tid; i < 64 * 8; i += 256) {
            int m = i >> 3, k4 = (i & 7) * 4;
            int r = row0 + m;
            int kk = k0 + k4;
            float4 v = make_float4(0.f, 0.f, 0.f, 0.f);
            if (r < M) {
                if (kk < 128) v = *(const float4*)&mfe[(size_t)r * 128 + kk];
                else          v = *(const float4*)&agg[(size_t)r * 128 + kk - 128];
            }
            As[k4][m] = v.x; As[k4 + 1][m] = v.y; As[k4 + 2][m] = v.z; As[k4 + 3][m] = v.w;
        }
        for (int i = tid; i < 64 * 8; i += 256) {
            int n = i >> 3, k4 = (i & 7) * 4;
            float4 v = *(const float4*)&W[(size_t)(col0 + n) * 256 + k0 + k4];
            Bs[k4][n] = v.x; Bs[k4 + 1][n] = v.y; Bs[k4 + 2][n] = v.z; Bs[k4 + 3][n] = v.w;
        }
        __syncthreads();
#pragma unroll
        for (int kk = 0; kk < 32; ++kk) {
            float av[4], bv[4];
#pragma unroll
            for (int i = 0; i < 4; ++i) av[i] = As[kk][tm0 + i];
#pragma unroll
            for (int j = 0; j < 4; ++j) bv[j] = Bs[kk][tn0 + j];
#pragma unroll
            for (int i = 0; i < 4; ++i)
#pragma unroll
                for (int j = 0; j < 4; ++j) acc[i][j] += av[i] * bv[j];
        }
        __syncthreads();
    }
#pragma unroll
    for (int i = 0; i < 4; ++i) {
        int r = row0 + tm0 + i;
        if (r < M) {
            ushort4 p;
            p.x = f2bf(acc[i][0] + bias[col0 + tn0 + 0]);
            p.y = f2bf(acc[i][1] + bias[col0 + tn0 + 1]);
            p.z = f2bf(acc[i][2] + bias[col0 + tn0 + 2]);
            p.w = f2bf(acc[i][3] + bias[col0 + tn0 + 3]);
            *(ushort4*)&C[(size_t)r * 256 + col0 + tn0] = p;
        }
    }
}

// -- h2 GEMM: A = [l_feats[gsrc]+l_feats[gdst] | m_feats] (K=256), bf16 out --
__global__ __launch_bounds__(256) void gemm_h2_bf16(
    const float* __restrict__ lf, const float* __restrict__ mfe,
    const int* __restrict__ gsrc, const int* __restrict__ gdst,
    const float* __restrict__ W, const float* __restrict__ bias,
    unsigned short* __restrict__ C, int M)
{
    __shared__ float As[32][65];
    __shared__ float Bs[32][65];
    const int row0 = blockIdx.x * 64;
    const int col0 = blockIdx.y * 64;
    const int tid = threadIdx.x;
    const int tx = tid & 15, ty = tid >> 4;
    const int tm0 = ty * 4, tn0 = tx * 4;
    float acc[4][4] = {};
#pragma unroll
    for (int k0 = 0; k0 < 256; k0 += 32) {
        for (int i = tid; i < 64 * 8; i += 256) {
            int m = i >> 3, k4 = (i & 7) * 4;
            int r = row0 + m;
            int kk = k0 + k4;
            float4 v = make_float4(0.f, 0.f, 0.f, 0.f);
            if (r < M) {
                if (kk < 128) {
                    float4 a = *(const float4*)&lf[(size_t)gsrc[r] * 128 + kk];
                    float4 b = *(const float4*)&lf[(size_t)gdst[r] * 128 + kk];
                    v = make_float4(a.x + b.x, a.y + b.y, a.z + b.z, a.w + b.w);
                } else {
                    v = *(const float4*)&mfe[(size_t)r * 128 + kk - 128];
                }
            }
            As[k4][m] = v.x; As[k4 + 1][m] = v.y; As[k4 + 2][m] = v.z; As[k4 + 3][m] = v.w;
        }
        for (int i = tid; i < 64 * 8; i += 256) {
            int n = i >> 3, k4 = (i & 7) * 4;
            float4 v = *(const float4*)&W[(size_t)(col0 + n) * 256 + k0 + k4];
            Bs[k4][n] = v.x; Bs[k4 + 1][n] = v.y; Bs[k4 + 2][n] = v.z; Bs[k4 + 3][n] = v.w;
        }
        __syncthreads();
#pragma unroll
        for (int kk = 0; kk < 32; ++kk) {
            float av[4], bv[4];
#pragma unroll
            for (int i = 0; i < 4; ++i) av[i] = As[kk][tm0 + i];
#pragma unroll
            for (int j = 0; j < 4; ++j) bv[j] = Bs[kk][tn0 + j];
#pragma unroll
            for (int i = 0; i < 4; ++i)
#pragma unroll
                for (int j = 0; j < 4; ++j) acc[i][j] += av[i] * bv[j];
        }
        __syncthreads();
    }
#pragma unroll
    for (int i = 0; i < 4; ++i) {
        int r = row0 + tm0 + i;
        if (r < M) {
            ushort4 p;
            p.x = f2bf(acc[i][0] + bias[col0 + tn0 + 0]);
            p.y = f2bf(acc[i][1] + bias[col0 + tn0 + 1]);
            p.z = f2bf(acc[i][2] + bias[col0 + tn0 + 2]);
            p.w = f2bf(acc[i][3] + bias[col0 + tn0 + 3]);
            *(ushort4*)&C[(size_t)r * 256 + col0 + tn0] = p;
        }
    }
}

// ---------- per-head scatter (wave per lg edge, 64 cols of head h) ----------
__global__ __launch_bounds__(256) void scatter_h(
    const unsigned short* __restrict__ h1, const unsigned short* __restrict__ h2,
    const float* __restrict__ exlg, const float* __restrict__ lgden,
    const int* __restrict__ src, const int* __restrict__ dst,
    float* __restrict__ h1d, float* __restrict__ h2d, int nE2, int h)
{
    const int lane = threadIdx.x & 63;
    const int e = blockIdx.x * 4 + (threadIdx.x >> 6);
    if (e >= nE2) return;
    const int s = src[e], d = dst[e];
    float a = exlg[(size_t)e * 4 + h] / lgden[(size_t)d * 4 + h];
    int c = h * 64 + lane;
    atomicAdd(&h1d[(size_t)d * 64 + lane], bf2f(h1[(size_t)s * 256 + c]) * a);
    atomicAdd(&h2d[(size_t)d * 64 + lane], bf2f(h2[(size_t)s * 256 + c]));
}

// ---------------- per-head epilogue, accumulate into out ----------------
__global__ __launch_bounds__(256) void final_h(
    const float* __restrict__ h1d, const float* __restrict__ h2d,
    const float* __restrict__ exg, const float* __restrict__ gden,
    const int* __restrict__ gdst, float* __restrict__ out, int nE, int h)
{
    const int lane = threadIdx.x & 63;
    const int j = blockIdx.x * 4 + (threadIdx.x >> 6);
    if (j >= nE) return;
    const int gd = gdst[j];
    float o = LRELU(h1d[(size_t)j * 64 + lane]);
    float ag = exg[(size_t)j * 4 + h] / gden[(size_t)gd * 4 + h];
    float v2 = ag * h2d[(size_t)j * 64 + lane];
    o += LRELU(v2);
    float* po = &out[(size_t)j * 64 + lane];
    if (h == 0) *po = o;
    else        *po += o;
}

extern "C" void kernel_launch(void* const* d_in, const int* in_sizes, int n_in,
                              void* d_out, int out_size, void* d_ws, size_t ws_size,
                              hipStream_t stream)
{
    const float* l_feats   = (const float*)d_in[0];
    const float* m_feats   = (const float*)d_in[1];
    const float* x_feats   = (const float*)d_in[2];
    const int*   g_src     = (const int*)d_in[3];
    const int*   g_dst     = (const int*)d_in[4];
    const int*   lg_src    = (const int*)d_in[5];
    const int*   lg_dst    = (const int*)d_in[6];
    const float* W_lg_node = (const float*)d_in[7];
    const float* b_lg_node = (const float*)d_in[8];
    const float* W_lg_ni   = (const float*)d_in[9];
    const float* W_lg_fij  = (const float*)d_in[10];
    const float* W_lg_nj   = (const float*)d_in[11];
    const float* lg_attn   = (const float*)d_in[12];
    const float* bias_lg   = (const float*)d_in[13];
    const float* W_g_node  = (const float*)d_in[14];
    const float* b_g_node  = (const float*)d_in[15];
    const float* W_g_ni    = (const float*)d_in[16];
    const float* W_g_fij   = (const float*)d_in[17];
    const float* W_g_nj    = (const float*)d_in[18];
    const float* g_attn    = (const float*)d_in[19];
    const float* bias_g    = (const float*)d_in[20];

    const int N  = in_sizes[0] / 128;
    const int E  = in_sizes[3];
    const int E2 = in_sizes[5];

    float* ws = (float*)d_ws;
    size_t off = 0;
    auto alloc = [&](size_t n) { float* p = ws + off; off += n; return p; };

    // arena (float slots). total ~67.5M floats = 270 MB
    unsigned short* ni_lg = (unsigned short*)alloc((size_t)E * 128);   // E x 256 bf16 -> reused as h1
    unsigned short* nj_lg = (unsigned short*)alloc((size_t)E * 128);   // E x 256 bf16 -> reused as h2
    unsigned short* gni   = (unsigned short*)alloc((size_t)N * 128);   // N x 256 bf16
    unsigned short* gnj   = (unsigned short*)alloc((size_t)N * 128);
    float* aggspace = alloc((size_t)E * 128);  // agg fp32 -> reused as h1d|h2d per head
    float* cnt   = alloc((size_t)E);
    float* e_lg  = alloc((size_t)E2 * 4);
    unsigned* lgmax = (unsigned*)alloc((size_t)E * 4);
    float* lgden = alloc((size_t)E * 4);
    float* e_g   = alloc((size_t)E * 4);
    unsigned* gmax = (unsigned*)alloc((size_t)N * 4);
    float* gden  = alloc((size_t)N * 4);

    unsigned short* h1 = ni_lg;
    unsigned short* h2 = nj_lg;
    float* agg = aggspace;
    float* h1d = aggspace;                      // E x 64 fp32
    float* h2d = aggspace + (size_t)E * 64;     // E x 64 fp32

    (void)n_in; (void)out_size; (void)ws_size;
    float* outp = (float*)d_out;
    dim3 blk(256);

    // zero-init accumulators (0-encoding of segment-max acts as -inf sentinel)
    hipMemsetAsync(agg,   0, (size_t)E * 128 * 4, stream);
    hipMemsetAsync(cnt,   0, (size_t)E * 4, stream);
    hipMemsetAsync(lgmax, 0, (size_t)E * 4 * 4, stream);
    hipMemsetAsync(lgden, 0, (size_t)E * 4 * 4, stream);
    hipMemsetAsync(gmax,  0, (size_t)N * 4 * 4, stream);
    hipMemsetAsync(gden,  0, (size_t)N * 4 * 4, stream);

    // projection GEMMs (K=128 -> 256 cols, bf16 out)
    gemm_f128_bf16<<<dim3((N + 63) / 64, 4), blk, 0, stream>>>(l_feats, W_g_ni, gni, N);
    gemm_f128_bf16<<<dim3((N + 63) / 64, 4), blk, 0, stream>>>(l_feats, W_g_nj, gnj, N);
    gemm_f128_bf16<<<dim3((E + 63) / 64, 4), blk, 0, stream>>>(m_feats, W_lg_ni, ni_lg, E);
    gemm_f128_bf16<<<dim3((E + 63) / 64, 4), blk, 0, stream>>>(m_feats, W_lg_nj, nj_lg, E);

    // fused fij GEMM + raw score + segment max (no fij buffer)
    gemm_score<<<dim3((E2 + 63) / 64, 4), blk, 0, stream>>>(
        x_feats, W_lg_fij, ni_lg, nj_lg, bias_lg, lg_attn, lg_src, lg_dst, e_lg, lgmax, E2);
    gemm_score<<<dim3((E + 63) / 64, 4), blk, 0, stream>>>(
        m_feats, W_g_fij, gni, gnj, bias_g, g_attn, g_src, g_dst, e_g, gmax, E);

    // softmax pass 2 (divide folded into consumers)
    edge_exp<<<(unsigned)(((long long)E2 * 4 + 255) / 256), blk, 0, stream>>>(e_lg, lgmax, lgden, lg_dst, E2);
    edge_exp<<<(unsigned)(((long long)E * 4 + 255) / 256), blk, 0, stream>>>(e_g, gmax, gden, g_dst, E);

    // mean aggregation of x onto lg_dst
    agg_x<<<(E2 + 1) / 2, blk, 0, stream>>>(x_feats, lg_dst, agg, cnt, E2);
    agg_div<<<(unsigned)(((long long)E * 128 + 255) / 256), blk, 0, stream>>>(agg, cnt, (long long)E * 128);

    // node-update GEMMs (overwrite ni_lg / nj_lg; safe after gemm_score)
    gemm_h1_bf16<<<dim3((E + 63) / 64, 4), blk, 0, stream>>>(m_feats, agg, W_lg_node, b_lg_node, h1, E);
    gemm_h2_bf16<<<dim3((E + 63) / 64, 4), blk, 0, stream>>>(l_feats, m_feats, g_src, g_dst,
                                                             W_g_node, b_g_node, h2, E);

    // head-chunked scatter + epilogue (h1d/h2d reuse agg space, dead after gemm_h1)
    for (int h = 0; h < 4; ++h) {
        hipMemsetAsync(h1d, 0, (size_t)E * 128 * 4, stream);  // covers h1d and h2d
        scatter_h<<<(E2 + 3) / 4, blk, 0, stream>>>(h1, h2, e_lg, lgden, lg_src, lg_dst,
                                                    h1d, h2d, E2, h);
        final_h<<<(E + 3) / 4, blk, 0, stream>>>(h1d, h2d, e_g, gden, g_dst, outp, E, h);
    }
}

// Round 3
// 2506.744 us; speedup vs baseline: 31.4816x; 31.4816x over previous
//
#include <hip/hip_runtime.h>
#include <math.h>

#define LRELU(x) ((x) > 0.0f ? (x) : 0.01f * (x))

typedef __attribute__((ext_vector_type(8))) short short8;
typedef __attribute__((ext_vector_type(4))) float f32x4;
typedef unsigned short ushort_t;

__device__ __forceinline__ unsigned fenc(float f) {
    unsigned u = __float_as_uint(f);
    return (u & 0x80000000u) ? ~u : (u | 0x80000000u);
}
__device__ __forceinline__ float fdec(unsigned u) {
    return __uint_as_float((u & 0x80000000u) ? (u & 0x7FFFFFFFu) : ~u);
}
__device__ __forceinline__ unsigned short f2bf(float f) {
    unsigned u = __float_as_uint(f);
    u += 0x7FFFu + ((u >> 16) & 1u);
    return (unsigned short)(u >> 16);
}
__device__ __forceinline__ float bf2f(unsigned short b) {
    return __uint_as_float(((unsigned)b) << 16);
}
__device__ __forceinline__ ushort4 cvt4(float4 v) {
    ushort4 p;
    p.x = f2bf(v.x); p.y = f2bf(v.y); p.z = f2bf(v.z); p.w = f2bf(v.w);
    return p;
}

// ---- fp32 -> bf16 bulk convert (weights) ----
__global__ __launch_bounds__(256) void f2bf_k(
    const float* __restrict__ in, unsigned short* __restrict__ out, int n)
{
    for (int i = blockIdx.x * 256 + threadIdx.x; i < n; i += gridDim.x * 256)
        out[i] = f2bf(in[i]);
}

// ============ MFMA GEMM: C[M,256](bf16) = A[M,128](fp32) @ Wbf[256,128]^T ============
// block: 256 thr = 4 waves, M-tile 64, N full 256. grid.x = ceil(M/64).
__global__ __launch_bounds__(256) void gemm128_mfma(
    const float* __restrict__ A, const unsigned short* __restrict__ Wbf,
    const float* __restrict__ biasf, unsigned short* __restrict__ Cout, int M)
{
    __shared__ __align__(16) unsigned short smem[64 * 264];
    const int row0 = blockIdx.x * 64;
    const int tid = threadIdx.x;
    const int wv = tid >> 6, lane = tid & 63;
    const int ln = lane & 15, quad = lane >> 4;

    // stage A (fp32->bf16), row stride 136
#pragma unroll 1
    for (int i = tid; i < 2048; i += 256) {
        int row = i >> 5, c4 = (i & 31) * 4;
        int r = row0 + row;
        float4 v = make_float4(0.f, 0.f, 0.f, 0.f);
        if (r < M) v = *(const float4*)&A[(size_t)r * 128 + c4];
        *(ushort4*)&smem[row * 136 + c4] = cvt4(v);
    }
    __syncthreads();

    f32x4 acc[16];
#pragma unroll
    for (int t = 0; t < 16; ++t) acc[t] = (f32x4){0.f, 0.f, 0.f, 0.f};

#pragma unroll 1
    for (int ks = 0; ks < 4; ++ks) {
        short8 a = *(const short8*)&smem[(wv * 16 + ln) * 136 + ks * 32 + quad * 8];
#pragma unroll
        for (int t = 0; t < 16; ++t) {
            short8 b = *(const short8*)&Wbf[(size_t)(t * 16 + ln) * 128 + ks * 32 + quad * 8];
            acc[t] = __builtin_amdgcn_mfma_f32_16x16x32_bf16(a, b, acc[t], 0, 0, 0);
        }
    }
    __syncthreads();  // As dead -> reuse as Cs[64][264]

#pragma unroll
    for (int t = 0; t < 16; ++t) {
        int col = t * 16 + ln;
        float bb = biasf ? biasf[col] : 0.0f;
#pragma unroll
        for (int rg = 0; rg < 4; ++rg)
            smem[(wv * 16 + quad * 4 + rg) * 264 + col] = f2bf(acc[t][rg] + bb);
    }
    __syncthreads();
#pragma unroll 1
    for (int i = tid; i < 2048; i += 256) {
        int row = i >> 5, c8 = (i & 31) * 8;
        int r = row0 + row;
        if (r < M) *(short8*)&Cout[(size_t)r * 256 + c8] = *(const short8*)&smem[row * 264 + c8];
    }
}

// ============ fused fij MFMA GEMM + attention score ============
__global__ __launch_bounds__(256) void gemm_score_mfma(
    const float* __restrict__ A, const unsigned short* __restrict__ Wbf,
    const unsigned short* __restrict__ fni, const unsigned short* __restrict__ fnj,
    const float* __restrict__ bias, const float* __restrict__ attn,
    const int* __restrict__ src, const int* __restrict__ dst,
    float* __restrict__ ebuf, unsigned* __restrict__ smax, int M)
{
    __shared__ __align__(16) unsigned short smem[64 * 264];
    const int row0 = blockIdx.x * 64;
    const int tid = threadIdx.x;
    const int wv = tid >> 6, lane = tid & 63;
    const int ln = lane & 15, quad = lane >> 4;

#pragma unroll 1
    for (int i = tid; i < 2048; i += 256) {
        int row = i >> 5, c4 = (i & 31) * 4;
        int r = row0 + row;
        float4 v = make_float4(0.f, 0.f, 0.f, 0.f);
        if (r < M) v = *(const float4*)&A[(size_t)r * 128 + c4];
        *(ushort4*)&smem[row * 136 + c4] = cvt4(v);
    }
    __syncthreads();

    f32x4 acc[16];
#pragma unroll
    for (int t = 0; t < 16; ++t) acc[t] = (f32x4){0.f, 0.f, 0.f, 0.f};

#pragma unroll 1
    for (int ks = 0; ks < 4; ++ks) {
        short8 a = *(const short8*)&smem[(wv * 16 + ln) * 136 + ks * 32 + quad * 8];
#pragma unroll
        for (int t = 0; t < 16; ++t) {
            short8 b = *(const short8*)&Wbf[(size_t)(t * 16 + ln) * 128 + ks * 32 + quad * 8];
            acc[t] = __builtin_amdgcn_mfma_f32_16x16x32_bf16(a, b, acc[t], 0, 0, 0);
        }
    }

    // epilogue in two 32-row halves; D stash fp32 Csf[32][260]
    float* Csf = (float*)smem;
#pragma unroll 1
    for (int half = 0; half < 2; ++half) {
        __syncthreads();
        if ((wv >> 1) == half) {
            int lr0 = (wv & 1) * 16 + quad * 4;
#pragma unroll
            for (int t = 0; t < 16; ++t)
#pragma unroll
                for (int rg = 0; rg < 4; ++rg)
                    Csf[(lr0 + rg) * 260 + t * 16 + ln] = acc[t][rg];
        }
        __syncthreads();
#pragma unroll 1
        for (int rr = 0; rr < 8; ++rr) {
            int lr = wv * 8 + rr;
            int r = row0 + half * 32 + lr;
            if (r < M) {
                int s = src[r], d = dst[r];
#pragma unroll
                for (int h = 0; h < 4; ++h) {
                    int c = h * 64 + lane;
                    float v = Csf[lr * 260 + c]
                            + bf2f(fni[(size_t)s * 256 + c])
                            + bf2f(fnj[(size_t)d * 256 + c])
                            + bias[c];
                    v = LRELU(v) * attn[c];
#pragma unroll
                    for (int off2 = 32; off2; off2 >>= 1) v += __shfl_down(v, off2, 64);
                    if (lane == 0) {
                        ebuf[(size_t)r * 4 + h] = v;
                        atomicMax(&smax[(size_t)d * 4 + h], fenc(v));
                    }
                }
            }
        }
    }
}

// ============ K=256 MFMA GEMM for h1 (mode 0) / h2 (mode 1), +bias, bf16 out ============
__global__ __launch_bounds__(256) void gemm256_mfma(
    const float* __restrict__ A0, const void* __restrict__ A1v,
    const int* __restrict__ gsrc, const int* __restrict__ gdst,
    const unsigned short* __restrict__ Wbf, const float* __restrict__ biasf,
    unsigned short* __restrict__ Cout, int M, int mode)
{
    __shared__ __align__(16) unsigned short smem[64 * 264];
    const int row0 = blockIdx.x * 64;
    const int tid = threadIdx.x;
    const int wv = tid >> 6, lane = tid & 63;
    const int ln = lane & 15, quad = lane >> 4;

    if (mode == 0) {
        // low 128: m_feats fp32 ; high 128: agg bf16 (A1v = ushort*)
        const unsigned short* A1 = (const unsigned short*)A1v;
#pragma unroll 1
        for (int i = tid; i < 2048; i += 256) {
            int row = i >> 5, c4 = (i & 31) * 4;
            int r = row0 + row;
            float4 v = make_float4(0.f, 0.f, 0.f, 0.f);
            if (r < M) v = *(const float4*)&A0[(size_t)r * 128 + c4];
            *(ushort4*)&smem[row * 264 + c4] = cvt4(v);
        }
#pragma unroll 1
        for (int i = tid; i < 1024; i += 256) {
            int row = i >> 4, c8 = (i & 15) * 8;
            int r = row0 + row;
            short8 v;
#pragma unroll
            for (int q = 0; q < 8; ++q) v[q] = 0;
            if (r < M) v = *(const short8*)&A1[(size_t)r * 128 + c8];
            *(short8*)&smem[row * 264 + 128 + c8] = v;
        }
    } else {
        // low 128: l_feats[gsrc]+l_feats[gdst] ; high 128: m_feats (A1v = float*)
        const float* A1 = (const float*)A1v;
#pragma unroll 1
        for (int i = tid; i < 2048; i += 256) {
            int row = i >> 5, c4 = (i & 31) * 4;
            int r = row0 + row;
            float4 v = make_float4(0.f, 0.f, 0.f, 0.f);
            if (r < M) {
                float4 a = *(const float4*)&A0[(size_t)gsrc[r] * 128 + c4];
                float4 b = *(const float4*)&A0[(size_t)gdst[r] * 128 + c4];
                v = make_float4(a.x + b.x, a.y + b.y, a.z + b.z, a.w + b.w);
            }
            *(ushort4*)&smem[row * 264 + c4] = cvt4(v);
        }
#pragma unroll 1
        for (int i = tid; i < 2048; i += 256) {
            int row = i >> 5, c4 = (i & 31) * 4;
            int r = row0 + row;
            float4 v = make_float4(0.f, 0.f, 0.f, 0.f);
            if (r < M) v = *(const float4*)&A1[(size_t)r * 128 + c4];
            *(ushort4*)&smem[row * 264 + 128 + c4] = cvt4(v);
        }
    }
    __syncthreads();

    f32x4 acc[16];
#pragma unroll
    for (int t = 0; t < 16; ++t) acc[t] = (f32x4){0.f, 0.f, 0.f, 0.f};

#pragma unroll 1
    for (int ks = 0; ks < 8; ++ks) {
        short8 a = *(const short8*)&smem[(wv * 16 + ln) * 264 + ks * 32 + quad * 8];
#pragma unroll
        for (int t = 0; t < 16; ++t) {
            short8 b = *(const short8*)&Wbf[(size_t)(t * 16 + ln) * 256 + ks * 32 + quad * 8];
            acc[t] = __builtin_amdgcn_mfma_f32_16x16x32_bf16(a, b, acc[t], 0, 0, 0);
        }
    }
    __syncthreads();

#pragma unroll
    for (int t = 0; t < 16; ++t) {
        int col = t * 16 + ln;
        float bb = biasf[col];
#pragma unroll
        for (int rg = 0; rg < 4; ++rg)
            smem[(wv * 16 + quad * 4 + rg) * 264 + col] = f2bf(acc[t][rg] + bb);
    }
    __syncthreads();
#pragma unroll 1
    for (int i = tid; i < 2048; i += 256) {
        int row = i >> 5, c8 = (i & 31) * 8;
        int r = row0 + row;
        if (r < M) *(short8*)&Cout[(size_t)r * 256 + c8] = *(const short8*)&smem[row * 264 + c8];
    }
}

// ---------------- softmax pass 2: exp(e-max), atomic denom ----------------
__global__ __launch_bounds__(256) void edge_exp(
    float* __restrict__ ebuf, const unsigned* __restrict__ smax,
    float* __restrict__ sden, const int* __restrict__ dst, int nE)
{
    int i = blockIdx.x * 256 + threadIdx.x;
    if (i >= nE * 4) return;
    int e = i >> 2, h = i & 3;
    int d = dst[e];
    float m = fdec(smax[(size_t)d * 4 + h]);
    float ex = expf(ebuf[i] - m);
    ebuf[i] = ex;
    atomicAdd(&sden[(size_t)d * 4 + h], ex);
}

// ---------------- mean-aggregate x_feats onto lg_dst ----------------
__global__ __launch_bounds__(256) void agg_x(
    const float* __restrict__ x, const int* __restrict__ dst,
    float* __restrict__ agg, float* __restrict__ cnt, int nE2)
{
    const int k = threadIdx.x & 127;
    const int e = blockIdx.x * 2 + (threadIdx.x >> 7);
    if (e >= nE2) return;
    const int d = dst[e];
    atomicAdd(&agg[(size_t)d * 128 + k], x[(size_t)e * 128 + k]);
    if (k == 0) atomicAdd(&cnt[d], 1.0f);
}

__global__ __launch_bounds__(256) void agg_div_bf(
    const float* __restrict__ agg, const float* __restrict__ cnt,
    unsigned short* __restrict__ aggbf, long long n)
{
    long long i = (long long)blockIdx.x * 256 + threadIdx.x;
    if (i >= n) return;
    float v = agg[i] / fmaxf(cnt[i >> 7], 1.0f);
    aggbf[i] = f2bf(v);
}

// ---------- per-head scatter (wave per lg edge, 64 cols of head h) ----------
__global__ __launch_bounds__(256) void scatter_h(
    const unsigned short* __restrict__ h1, const unsigned short* __restrict__ h2,
    const float* __restrict__ exlg, const float* __restrict__ lgden,
    const int* __restrict__ src, const int* __restrict__ dst,
    float* __restrict__ h1d, float* __restrict__ h2d, int nE2, int h)
{
    const int lane = threadIdx.x & 63;
    const int e = blockIdx.x * 4 + (threadIdx.x >> 6);
    if (e >= nE2) return;
    const int s = src[e], d = dst[e];
    float a = exlg[(size_t)e * 4 + h] / lgden[(size_t)d * 4 + h];
    int c = h * 64 + lane;
    atomicAdd(&h1d[(size_t)d * 64 + lane], bf2f(h1[(size_t)s * 256 + c]) * a);
    atomicAdd(&h2d[(size_t)d * 64 + lane], bf2f(h2[(size_t)s * 256 + c]));
}

// ---------------- per-head epilogue, accumulate into out ----------------
__global__ __launch_bounds__(256) void final_h(
    const float* __restrict__ h1d, const float* __restrict__ h2d,
    const float* __restrict__ exg, const float* __restrict__ gden,
    const int* __restrict__ gdst, float* __restrict__ out, int nE, int h)
{
    const int lane = threadIdx.x & 63;
    const int j = blockIdx.x * 4 + (threadIdx.x >> 6);
    if (j >= nE) return;
    const int gd = gdst[j];
    float o = LRELU(h1d[(size_t)j * 64 + lane]);
    float ag = exg[(size_t)j * 4 + h] / gden[(size_t)gd * 4 + h];
    float v2 = ag * h2d[(size_t)j * 64 + lane];
    o += LRELU(v2);
    float* po = &out[(size_t)j * 64 + lane];
    if (h == 0) *po = o;
    else        *po += o;
}

extern "C" void kernel_launch(void* const* d_in, const int* in_sizes, int n_in,
                              void* d_out, int out_size, void* d_ws, size_t ws_size,
                              hipStream_t stream)
{
    const float* l_feats   = (const float*)d_in[0];
    const float* m_feats   = (const float*)d_in[1];
    const float* x_feats   = (const float*)d_in[2];
    const int*   g_src     = (const int*)d_in[3];
    const int*   g_dst     = (const int*)d_in[4];
    const int*   lg_src    = (const int*)d_in[5];
    const int*   lg_dst    = (const int*)d_in[6];
    const float* W_lg_node = (const float*)d_in[7];
    const float* b_lg_node = (const float*)d_in[8];
    const float* W_lg_ni   = (const float*)d_in[9];
    const float* W_lg_fij  = (const float*)d_in[10];
    const float* W_lg_nj   = (const float*)d_in[11];
    const float* lg_attn   = (const float*)d_in[12];
    const float* bias_lg   = (const float*)d_in[13];
    const float* W_g_node  = (const float*)d_in[14];
    const float* b_g_node  = (const float*)d_in[15];
    const float* W_g_ni    = (const float*)d_in[16];
    const float* W_g_fij   = (const float*)d_in[17];
    const float* W_g_nj    = (const float*)d_in[18];
    const float* g_attn    = (const float*)d_in[19];
    const float* bias_g    = (const float*)d_in[20];

    const int N  = in_sizes[0] / 128;
    const int E  = in_sizes[3];
    const int E2 = in_sizes[5];

    float* ws = (float*)d_ws;
    size_t off = 0;
    auto alloc = [&](size_t n) { float* p = ws + off; off += n; return p; };

    // bf16 weights (ushort units within a float-slot arena)
    unsigned short* wbuf = (unsigned short*)alloc(163840);
    unsigned short* wgni_bf    = wbuf;
    unsigned short* wgnj_bf    = wbuf + 32768;
    unsigned short* wlgni_bf   = wbuf + 65536;
    unsigned short* wlgnj_bf   = wbuf + 98304;
    unsigned short* wlgfij_bf  = wbuf + 131072;
    unsigned short* wgfij_bf   = wbuf + 163840;
    unsigned short* wlgnode_bf = wbuf + 196608;
    unsigned short* wgnode_bf  = wbuf + 262144;

    unsigned short* ni_lg = (unsigned short*)alloc((size_t)E * 128);  // [E,256] bf16 -> h1
    unsigned short* nj_lg = (unsigned short*)alloc((size_t)E * 128);  // [E,256] bf16 -> h2
    unsigned short* gni   = (unsigned short*)alloc((size_t)N * 128);
    unsigned short* gnj   = (unsigned short*)alloc((size_t)N * 128);
    float* aggspace = alloc((size_t)E * 128);                          // agg fp32 -> h1d|h2d
    unsigned short* aggbf = (unsigned short*)alloc((size_t)E * 64);    // [E,128] bf16
    float* cnt   = alloc((size_t)E);
    float* e_lg  = alloc((size_t)E2 * 4);
    unsigned* lgmax = (unsigned*)alloc((size_t)E * 4);
    float* lgden = alloc((size_t)E * 4);
    float* e_g   = alloc((size_t)E * 4);
    unsigned* gmax = (unsigned*)alloc((size_t)N * 4);
    float* gden  = alloc((size_t)N * 4);

    unsigned short* h1 = ni_lg;
    unsigned short* h2 = nj_lg;
    float* agg = aggspace;
    float* h1d = aggspace;
    float* h2d = aggspace + (size_t)E * 64;

    (void)n_in; (void)out_size; (void)ws_size;
    float* outp = (float*)d_out;
    dim3 blk(256);

    hipMemsetAsync(agg,   0, (size_t)E * 128 * 4, stream);
    hipMemsetAsync(cnt,   0, (size_t)E * 4, stream);
    hipMemsetAsync(lgmax, 0, (size_t)E * 4 * 4, stream);
    hipMemsetAsync(lgden, 0, (size_t)E * 4 * 4, stream);
    hipMemsetAsync(gmax,  0, (size_t)N * 4 * 4, stream);
    hipMemsetAsync(gden,  0, (size_t)N * 4 * 4, stream);

    // convert weights to bf16
    f2bf_k<<<128, blk, 0, stream>>>(W_g_ni,    wgni_bf,    32768);
    f2bf_k<<<128, blk, 0, stream>>>(W_g_nj,    wgnj_bf,    32768);
    f2bf_k<<<128, blk, 0, stream>>>(W_lg_ni,   wlgni_bf,   32768);
    f2bf_k<<<128, blk, 0, stream>>>(W_lg_nj,   wlgnj_bf,   32768);
    f2bf_k<<<128, blk, 0, stream>>>(W_lg_fij,  wlgfij_bf,  32768);
    f2bf_k<<<128, blk, 0, stream>>>(W_g_fij,   wgfij_bf,   32768);
    f2bf_k<<<256, blk, 0, stream>>>(W_lg_node, wlgnode_bf, 65536);
    f2bf_k<<<256, blk, 0, stream>>>(W_g_node,  wgnode_bf,  65536);

    // projection GEMMs (K=128 -> 256 cols, bf16 out, no bias)
    gemm128_mfma<<<(N + 63) / 64, blk, 0, stream>>>(l_feats, wgni_bf, nullptr, gni, N);
    gemm128_mfma<<<(N + 63) / 64, blk, 0, stream>>>(l_feats, wgnj_bf, nullptr, gnj, N);
    gemm128_mfma<<<(E + 63) / 64, blk, 0, stream>>>(m_feats, wlgni_bf, nullptr, ni_lg, E);
    gemm128_mfma<<<(E + 63) / 64, blk, 0, stream>>>(m_feats, wlgnj_bf, nullptr, nj_lg, E);

    // fused fij GEMM + raw score + segment max
    gemm_score_mfma<<<(E2 + 63) / 64, blk, 0, stream>>>(
        x_feats, wlgfij_bf, ni_lg, nj_lg, bias_lg, lg_attn, lg_src, lg_dst, e_lg, lgmax, E2);
    gemm_score_mfma<<<(E + 63) / 64, blk, 0, stream>>>(
        m_feats, wgfij_bf, gni, gnj, bias_g, g_attn, g_src, g_dst, e_g, gmax, E);

    // softmax pass 2
    edge_exp<<<(unsigned)(((long long)E2 * 4 + 255) / 256), blk, 0, stream>>>(e_lg, lgmax, lgden, lg_dst, E2);
    edge_exp<<<(unsigned)(((long long)E * 4 + 255) / 256), blk, 0, stream>>>(e_g, gmax, gden, g_dst, E);

    // mean aggregation of x onto lg_dst
    agg_x<<<(E2 + 1) / 2, blk, 0, stream>>>(x_feats, lg_dst, agg, cnt, E2);
    agg_div_bf<<<(unsigned)(((long long)E * 128 + 255) / 256), blk, 0, stream>>>(agg, cnt, aggbf, (long long)E * 128);

    // node-update GEMMs (K=256; overwrite ni_lg/nj_lg -> h1/h2)
    gemm256_mfma<<<(E + 63) / 64, blk, 0, stream>>>(
        m_feats, (const void*)aggbf, nullptr, nullptr, wlgnode_bf, b_lg_node, h1, E, 0);
    gemm256_mfma<<<(E + 63) / 64, blk, 0, stream>>>(
        l_feats, (const void*)m_feats, g_src, g_dst, wgnode_bf, b_g_node, h2, E, 1);

    // head-chunked scatter + epilogue (h1d/h2d reuse agg fp32 space)
    for (int h = 0; h < 4; ++h) {
        hipMemsetAsync(h1d, 0, (size_t)E * 128 * 4, stream);
        scatter_h<<<(E2 + 3) / 4, blk, 0, stream>>>(h1, h2, e_lg, lgden, lg_src, lg_dst,
                                                    h1d, h2d, E2, h);
        final_h<<<(E + 3) / 4, blk, 0, stream>>>(h1d, h2d, e_g, gden, g_dst, outp, E, h);
    }
}

// Round 4
// 1670.347 us; speedup vs baseline: 47.2455x; 1.5007x over previous
//
#include <hip/hip_runtime.h>
#include <math.h>

#define LRELU(x) ((x) > 0.0f ? (x) : 0.01f * (x))

typedef __attribute__((ext_vector_type(8))) short short8;
typedef __attribute__((ext_vector_type(4))) float f32x4;

__device__ __forceinline__ unsigned fenc(float f) {
    unsigned u = __float_as_uint(f);
    return (u & 0x80000000u) ? ~u : (u | 0x80000000u);
}
__device__ __forceinline__ float fdec(unsigned u) {
    return __uint_as_float((u & 0x80000000u) ? (u & 0x7FFFFFFFu) : ~u);
}
__device__ __forceinline__ unsigned short f2bf(float f) {
    unsigned u = __float_as_uint(f);
    u += 0x7FFFu + ((u >> 16) & 1u);
    return (unsigned short)(u >> 16);
}
__device__ __forceinline__ float bf2f(unsigned short b) {
    return __uint_as_float(((unsigned)b) << 16);
}
__device__ __forceinline__ ushort4 cvt4(float4 v) {
    ushort4 p;
    p.x = f2bf(v.x); p.y = f2bf(v.y); p.z = f2bf(v.z); p.w = f2bf(v.w);
    return p;
}

// ---- fp32 -> bf16 bulk convert (weights) ----
__global__ __launch_bounds__(256) void f2bf_k(
    const float* __restrict__ in, unsigned short* __restrict__ out, int n)
{
    for (int i = blockIdx.x * 256 + threadIdx.x; i < n; i += gridDim.x * 256)
        out[i] = f2bf(in[i]);
}

// ============ MFMA GEMM: C[M,256](bf16) = A[M,128](fp32) @ Wbf[256,128]^T ============
__global__ __launch_bounds__(256) void gemm128_mfma(
    const float* __restrict__ A, const unsigned short* __restrict__ Wbf,
    const float* __restrict__ biasf, unsigned short* __restrict__ Cout, int M)
{
    __shared__ __align__(16) unsigned short smem[64 * 264];
    const int row0 = blockIdx.x * 64;
    const int tid = threadIdx.x;
    const int wv = tid >> 6, lane = tid & 63;
    const int ln = lane & 15, quad = lane >> 4;

#pragma unroll 1
    for (int i = tid; i < 2048; i += 256) {
        int row = i >> 5, c4 = (i & 31) * 4;
        int r = row0 + row;
        float4 v = make_float4(0.f, 0.f, 0.f, 0.f);
        if (r < M) v = *(const float4*)&A[(size_t)r * 128 + c4];
        *(ushort4*)&smem[row * 136 + c4] = cvt4(v);
    }
    __syncthreads();

    f32x4 acc[16];
#pragma unroll
    for (int t = 0; t < 16; ++t) acc[t] = (f32x4){0.f, 0.f, 0.f, 0.f};

#pragma unroll 1
    for (int ks = 0; ks < 4; ++ks) {
        short8 a = *(const short8*)&smem[(wv * 16 + ln) * 136 + ks * 32 + quad * 8];
#pragma unroll
        for (int t = 0; t < 16; ++t) {
            short8 b = *(const short8*)&Wbf[(size_t)(t * 16 + ln) * 128 + ks * 32 + quad * 8];
            acc[t] = __builtin_amdgcn_mfma_f32_16x16x32_bf16(a, b, acc[t], 0, 0, 0);
        }
    }
    __syncthreads();

#pragma unroll
    for (int t = 0; t < 16; ++t) {
        int col = t * 16 + ln;
        float bb = biasf ? biasf[col] : 0.0f;
#pragma unroll
        for (int rg = 0; rg < 4; ++rg)
            smem[(wv * 16 + quad * 4 + rg) * 264 + col] = f2bf(acc[t][rg] + bb);
    }
    __syncthreads();
#pragma unroll 1
    for (int i = tid; i < 2048; i += 256) {
        int row = i >> 5, c8 = (i & 31) * 8;
        int r = row0 + row;
        if (r < M) *(short8*)&Cout[(size_t)r * 256 + c8] = *(const short8*)&smem[row * 264 + c8];
    }
}

// ============ fused fij MFMA GEMM + attention score (in-register epilogue) ============
// writes RAW scores to ebuf; if domax, also atomicMax into smax (encoded).
__global__ __launch_bounds__(256) void gemm_score_mfma(
    const float* __restrict__ A, const unsigned short* __restrict__ Wbf,
    const unsigned short* __restrict__ fni, const unsigned short* __restrict__ fnj,
    const float* __restrict__ bias, const float* __restrict__ attn,
    const int* __restrict__ src, const int* __restrict__ dst,
    float* __restrict__ ebuf, unsigned* __restrict__ smax, int M, int domax)
{
    __shared__ __align__(16) unsigned short smem[256 * 68]; // A-stage [64][136] then gsumT [256][68]
    const int row0 = blockIdx.x * 64;
    const int tid = threadIdx.x;
    const int wv = tid >> 6, lane = tid & 63;
    const int ln = lane & 15, quad = lane >> 4;

#pragma unroll 1
    for (int i = tid; i < 2048; i += 256) {
        int row = i >> 5, c4 = (i & 31) * 4;
        int r = row0 + row;
        float4 v = make_float4(0.f, 0.f, 0.f, 0.f);
        if (r < M) v = *(const float4*)&A[(size_t)r * 128 + c4];
        *(ushort4*)&smem[row * 136 + c4] = cvt4(v);
    }
    __syncthreads();

    f32x4 acc[16];
#pragma unroll
    for (int t = 0; t < 16; ++t) acc[t] = (f32x4){0.f, 0.f, 0.f, 0.f};

#pragma unroll 1
    for (int ks = 0; ks < 4; ++ks) {
        short8 a = *(const short8*)&smem[(wv * 16 + ln) * 136 + ks * 32 + quad * 8];
#pragma unroll
        for (int t = 0; t < 16; ++t) {
            short8 b = *(const short8*)&Wbf[(size_t)(t * 16 + ln) * 128 + ks * 32 + quad * 8];
            acc[t] = __builtin_amdgcn_mfma_f32_16x16x32_bf16(a, b, acc[t], 0, 0, 0);
        }
    }
    __syncthreads();  // A-stage dead

    // stage gsumT[col][row] = bf16(fni[src[row]][col] + fnj[dst[row]][col] + bias[col])
#pragma unroll 1
    for (int i = tid; i < 2048; i += 256) {
        int row = i >> 5, c8 = (i & 31) * 8;
        int r = row0 + row;
        unsigned short o[8];
        if (r < M) {
            int s = src[r], dd = dst[r];
            short8 u = *(const short8*)&fni[(size_t)s * 256 + c8];
            short8 v = *(const short8*)&fnj[(size_t)dd * 256 + c8];
#pragma unroll
            for (int q = 0; q < 8; ++q)
                o[q] = f2bf(bf2f((unsigned short)u[q]) + bf2f((unsigned short)v[q]) + bias[c8 + q]);
        } else {
#pragma unroll
            for (int q = 0; q < 8; ++q) o[q] = 0;
        }
#pragma unroll
        for (int q = 0; q < 8; ++q) smem[(c8 + q) * 68 + row] = o[q];
    }
    __syncthreads();

    float attn_r[16];
#pragma unroll
    for (int t = 0; t < 16; ++t) attn_r[t] = attn[t * 16 + ln];

    float hs[16];  // [h*4+rg]
#pragma unroll
    for (int j = 0; j < 16; ++j) hs[j] = 0.0f;

#pragma unroll
    for (int t = 0; t < 16; ++t) {
        ushort4 g4 = *(const ushort4*)&smem[(t * 16 + ln) * 68 + wv * 16 + quad * 4];
        unsigned short gu[4] = {g4.x, g4.y, g4.z, g4.w};
        int h = t >> 2;
#pragma unroll
        for (int rg = 0; rg < 4; ++rg) {
            float v = acc[t][rg] + bf2f(gu[rg]);
            v = LRELU(v) * attn_r[t];
            hs[h * 4 + rg] += v;
        }
    }
    // reduce over ln (lane bits 0..3) — 16 independent 4-step chains
#pragma unroll
    for (int j = 0; j < 16; ++j) {
        hs[j] += __shfl_xor(hs[j], 1, 64);
        hs[j] += __shfl_xor(hs[j], 2, 64);
        hs[j] += __shfl_xor(hs[j], 4, 64);
        hs[j] += __shfl_xor(hs[j], 8, 64);
    }
    if (ln == 0) {
#pragma unroll
        for (int rg = 0; rg < 4; ++rg) {
            int r = row0 + wv * 16 + quad * 4 + rg;
            if (r < M) {
                int dd = dst[r];
#pragma unroll
                for (int h = 0; h < 4; ++h) {
                    float val = hs[h * 4 + rg];
                    ebuf[(size_t)r * 4 + h] = val;
                    if (domax) atomicMax(&smax[(size_t)dd * 4 + h], fenc(val));
                }
            }
        }
    }
}

// ============ K=256 MFMA GEMM for h1 (mode 0) / h2 (mode 1), +bias, bf16 out ============
__global__ __launch_bounds__(256) void gemm256_mfma(
    const float* __restrict__ A0, const void* __restrict__ A1v,
    const int* __restrict__ gsrc, const int* __restrict__ gdst,
    const unsigned short* __restrict__ Wbf, const float* __restrict__ biasf,
    unsigned short* __restrict__ Cout, int M, int mode)
{
    __shared__ __align__(16) unsigned short smem[64 * 264];
    const int row0 = blockIdx.x * 64;
    const int tid = threadIdx.x;
    const int wv = tid >> 6, lane = tid & 63;
    const int ln = lane & 15, quad = lane >> 4;

    if (mode == 0) {
        const unsigned short* A1 = (const unsigned short*)A1v;
#pragma unroll 1
        for (int i = tid; i < 2048; i += 256) {
            int row = i >> 5, c4 = (i & 31) * 4;
            int r = row0 + row;
            float4 v = make_float4(0.f, 0.f, 0.f, 0.f);
            if (r < M) v = *(const float4*)&A0[(size_t)r * 128 + c4];
            *(ushort4*)&smem[row * 264 + c4] = cvt4(v);
        }
#pragma unroll 1
        for (int i = tid; i < 1024; i += 256) {
            int row = i >> 4, c8 = (i & 15) * 8;
            int r = row0 + row;
            short8 v;
#pragma unroll
            for (int q = 0; q < 8; ++q) v[q] = 0;
            if (r < M) v = *(const short8*)&A1[(size_t)r * 128 + c8];
            *(short8*)&smem[row * 264 + 128 + c8] = v;
        }
    } else {
        const float* A1 = (const float*)A1v;
#pragma unroll 1
        for (int i = tid; i < 2048; i += 256) {
            int row = i >> 5, c4 = (i & 31) * 4;
            int r = row0 + row;
            float4 v = make_float4(0.f, 0.f, 0.f, 0.f);
            if (r < M) {
                float4 a = *(const float4*)&A0[(size_t)gsrc[r] * 128 + c4];
                float4 b = *(const float4*)&A0[(size_t)gdst[r] * 128 + c4];
                v = make_float4(a.x + b.x, a.y + b.y, a.z + b.z, a.w + b.w);
            }
            *(ushort4*)&smem[row * 264 + c4] = cvt4(v);
        }
#pragma unroll 1
        for (int i = tid; i < 2048; i += 256) {
            int row = i >> 5, c4 = (i & 31) * 4;
            int r = row0 + row;
            float4 v = make_float4(0.f, 0.f, 0.f, 0.f);
            if (r < M) v = *(const float4*)&A1[(size_t)r * 128 + c4];
            *(ushort4*)&smem[row * 264 + 128 + c4] = cvt4(v);
        }
    }
    __syncthreads();

    f32x4 acc[16];
#pragma unroll
    for (int t = 0; t < 16; ++t) acc[t] = (f32x4){0.f, 0.f, 0.f, 0.f};

#pragma unroll 1
    for (int ks = 0; ks < 8; ++ks) {
        short8 a = *(const short8*)&smem[(wv * 16 + ln) * 264 + ks * 32 + quad * 8];
#pragma unroll
        for (int t = 0; t < 16; ++t) {
            short8 b = *(const short8*)&Wbf[(size_t)(t * 16 + ln) * 256 + ks * 32 + quad * 8];
            acc[t] = __builtin_amdgcn_mfma_f32_16x16x32_bf16(a, b, acc[t], 0, 0, 0);
        }
    }
    __syncthreads();

#pragma unroll
    for (int t = 0; t < 16; ++t) {
        int col = t * 16 + ln;
        float bb = biasf[col];
#pragma unroll
        for (int rg = 0; rg < 4; ++rg)
            smem[(wv * 16 + quad * 4 + rg) * 264 + col] = f2bf(acc[t][rg] + bb);
    }
    __syncthreads();
#pragma unroll 1
    for (int i = tid; i < 2048; i += 256) {
        int row = i >> 5, c8 = (i & 31) * 8;
        int r = row0 + row;
        if (r < M) *(short8*)&Cout[(size_t)r * 256 + c8] = *(const short8*)&smem[row * 264 + c8];
    }
}

// ---------------- softmax pass 2 (g branch): exp(e-max), atomic denom ----------------
__global__ __launch_bounds__(256) void edge_exp(
    float* __restrict__ ebuf, const unsigned* __restrict__ smax,
    float* __restrict__ sden, const int* __restrict__ dst, int nE)
{
    int i = blockIdx.x * 256 + threadIdx.x;
    if (i >= nE * 4) return;
    int e = i >> 2, h = i & 3;
    int d = dst[e];
    float m = fdec(smax[(size_t)d * 4 + h]);
    float ex = expf(ebuf[i] - m);
    ebuf[i] = ex;
    atomicAdd(&sden[(size_t)d * 4 + h], ex);
}

// ================= CSR build over lg_dst =================
__global__ __launch_bounds__(256) void count_k(
    const int* __restrict__ dst, int* __restrict__ cnt, int n)
{
    int i = blockIdx.x * 256 + threadIdx.x;
    if (i < n) atomicAdd(&cnt[dst[i]], 1);
}

__global__ __launch_bounds__(256) void scan1(
    const int* __restrict__ cnt, int* __restrict__ excl, int* __restrict__ bsum, int n)
{
    __shared__ int sd[256];
    int tid = threadIdx.x;
    int i = blockIdx.x * 256 + tid;
    int v = (i < n) ? cnt[i] : 0;
    sd[tid] = v;
    __syncthreads();
    for (int off2 = 1; off2 < 256; off2 <<= 1) {
        int t = (tid >= off2) ? sd[tid - off2] : 0;
        __syncthreads();
        sd[tid] += t;
        __syncthreads();
    }
    if (i < n) excl[i] = sd[tid] - v;
    if (tid == 255) bsum[blockIdx.x] = sd[255];
}

__global__ __launch_bounds__(1024) void scan2(int* __restrict__ bsum, int nb)
{
    __shared__ int sd[1024];
    int tid = threadIdx.x;
    int v = (tid < nb) ? bsum[tid] : 0;
    sd[tid] = v;
    __syncthreads();
    for (int off2 = 1; off2 < 1024; off2 <<= 1) {
        int t = (tid >= off2) ? sd[tid - off2] : 0;
        __syncthreads();
        sd[tid] += t;
        __syncthreads();
    }
    if (tid < nb) bsum[tid] = sd[tid] - v;  // exclusive
}

__global__ __launch_bounds__(256) void scan3(
    int* __restrict__ excl, const int* __restrict__ bsum, int n, int total)
{
    int i = blockIdx.x * 256 + threadIdx.x;
    if (i < n) excl[i] += bsum[i >> 8];
    if (i == 0) excl[n] = total;
}

__global__ __launch_bounds__(256) void fill_k(
    const int* __restrict__ dst, const int* __restrict__ row_ptr,
    int* __restrict__ cursor, int* __restrict__ colidx, int n)
{
    int i = blockIdx.x * 256 + threadIdx.x;
    if (i >= n) return;
    int d = dst[i];
    int p = atomicAdd(&cursor[d], 1);
    colidx[row_ptr[d] + p] = i;
}

// ---------------- CSR mean-gather of x_feats onto lg_dst (bf16 out) ----------------
__global__ __launch_bounds__(256) void agg_gather(
    const int* __restrict__ row_ptr, const int* __restrict__ colidx,
    const float* __restrict__ x, unsigned short* __restrict__ aggbf, int nE)
{
    const int lane = threadIdx.x & 63;
    const int d = blockIdx.x * 4 + (threadIdx.x >> 6);
    if (d >= nE) return;
    int b = row_ptr[d], en = row_ptr[d + 1];
    float s0 = 0.f, s1 = 0.f;
    for (int k = b; k < en; ++k) {
        int e = colidx[k];
        float2 v = *(const float2*)&x[(size_t)e * 128 + lane * 2];
        s0 += v.x; s1 += v.y;
    }
    float c = fmaxf((float)(en - b), 1.0f);
    ushort2 o;
    o.x = f2bf(s0 / c); o.y = f2bf(s1 / c);
    *(ushort2*)&aggbf[(size_t)d * 128 + lane * 2] = o;
}

// ---------------- final: local lg-softmax + weighted gather + epilogue ----------------
__global__ __launch_bounds__(256) void final_agg(
    const int* __restrict__ row_ptr, const int* __restrict__ colidx,
    const int* __restrict__ lg_src, const float* __restrict__ e_lg,
    const unsigned short* __restrict__ h1, const unsigned short* __restrict__ h2,
    const float* __restrict__ e_g, const float* __restrict__ gden,
    const int* __restrict__ g_dst, float* __restrict__ out, int nE)
{
    const int lane = threadIdx.x & 63;
    const int d = blockIdx.x * 4 + (threadIdx.x >> 6);
    if (d >= nE) return;
    int b = row_ptr[d], en = row_ptr[d + 1];

    float mx0 = -1e30f, mx1 = -1e30f, mx2 = -1e30f, mx3 = -1e30f;
    for (int k = b; k < en; ++k) {
        float4 sc = *(const float4*)&e_lg[(size_t)colidx[k] * 4];
        mx0 = fmaxf(mx0, sc.x); mx1 = fmaxf(mx1, sc.y);
        mx2 = fmaxf(mx2, sc.z); mx3 = fmaxf(mx3, sc.w);
    }
    float den0 = 0.f, den1 = 0.f, den2 = 0.f, den3 = 0.f;
    float a10 = 0.f, a11 = 0.f, a12 = 0.f, a13 = 0.f;
    float a20 = 0.f, a21 = 0.f, a22 = 0.f, a23 = 0.f;
    for (int k = b; k < en; ++k) {
        int e = colidx[k];
        float4 sc = *(const float4*)&e_lg[(size_t)e * 4];
        float w0 = expf(sc.x - mx0), w1 = expf(sc.y - mx1);
        float w2 = expf(sc.z - mx2), w3 = expf(sc.w - mx3);
        den0 += w0; den1 += w1; den2 += w2; den3 += w3;
        int s = lg_src[e];
        const unsigned short* p1 = &h1[(size_t)s * 256 + lane];
        const unsigned short* p2 = &h2[(size_t)s * 256 + lane];
        a10 += bf2f(p1[0])   * w0;
        a11 += bf2f(p1[64])  * w1;
        a12 += bf2f(p1[128]) * w2;
        a13 += bf2f(p1[192]) * w3;
        a20 += bf2f(p2[0]);
        a21 += bf2f(p2[64]);
        a22 += bf2f(p2[128]);
        a23 += bf2f(p2[192]);
    }
    float o = 0.f;
    if (en > b) {
        float v0 = a10 / den0, v1 = a11 / den1, v2 = a12 / den2, v3 = a13 / den3;
        o += LRELU(v0) + LRELU(v1) + LRELU(v2) + LRELU(v3);
    }
    int gd = g_dst[d];
    float g0 = e_g[(size_t)d * 4 + 0] / gden[(size_t)gd * 4 + 0] * a20;
    float g1 = e_g[(size_t)d * 4 + 1] / gden[(size_t)gd * 4 + 1] * a21;
    float g2 = e_g[(size_t)d * 4 + 2] / gden[(size_t)gd * 4 + 2] * a22;
    float g3 = e_g[(size_t)d * 4 + 3] / gden[(size_t)gd * 4 + 3] * a23;
    o += LRELU(g0) + LRELU(g1) + LRELU(g2) + LRELU(g3);
    out[(size_t)d * 64 + lane] = o;
}

extern "C" void kernel_launch(void* const* d_in, const int* in_sizes, int n_in,
                              void* d_out, int out_size, void* d_ws, size_t ws_size,
                              hipStream_t stream)
{
    const float* l_feats   = (const float*)d_in[0];
    const float* m_feats   = (const float*)d_in[1];
    const float* x_feats   = (const float*)d_in[2];
    const int*   g_src     = (const int*)d_in[3];
    const int*   g_dst     = (const int*)d_in[4];
    const int*   lg_src    = (const int*)d_in[5];
    const int*   lg_dst    = (const int*)d_in[6];
    const float* W_lg_node = (const float*)d_in[7];
    const float* b_lg_node = (const float*)d_in[8];
    const float* W_lg_ni   = (const float*)d_in[9];
    const float* W_lg_fij  = (const float*)d_in[10];
    const float* W_lg_nj   = (const float*)d_in[11];
    const float* lg_attn   = (const float*)d_in[12];
    const float* bias_lg   = (const float*)d_in[13];
    const float* W_g_node  = (const float*)d_in[14];
    const float* b_g_node  = (const float*)d_in[15];
    const float* W_g_ni    = (const float*)d_in[16];
    const float* W_g_fij   = (const float*)d_in[17];
    const float* W_g_nj    = (const float*)d_in[18];
    const float* g_attn    = (const float*)d_in[19];
    const float* bias_g    = (const float*)d_in[20];

    const int N  = in_sizes[0] / 128;
    const int E  = in_sizes[3];
    const int E2 = in_sizes[5];

    float* ws = (float*)d_ws;
    size_t off = 0;
    auto alloc = [&](size_t n) { float* p = ws + off; off += n; return p; };

    // bf16 weights (ushort offsets within a float-slot arena)
    unsigned short* wbuf = (unsigned short*)alloc(163840);
    unsigned short* wgni_bf    = wbuf;
    unsigned short* wgnj_bf    = wbuf + 32768;
    unsigned short* wlgni_bf   = wbuf + 65536;
    unsigned short* wlgnj_bf   = wbuf + 98304;
    unsigned short* wlgfij_bf  = wbuf + 131072;
    unsigned short* wgfij_bf   = wbuf + 163840;
    unsigned short* wlgnode_bf = wbuf + 196608;
    unsigned short* wgnode_bf  = wbuf + 262144;

    unsigned short* ni_lg = (unsigned short*)alloc((size_t)E * 128);  // [E,256] bf16 -> h1
    unsigned short* nj_lg = (unsigned short*)alloc((size_t)E * 128);  // [E,256] bf16 -> h2
    unsigned short* gni   = (unsigned short*)alloc((size_t)N * 128);
    unsigned short* gnj   = (unsigned short*)alloc((size_t)N * 128);
    unsigned short* aggbf = (unsigned short*)alloc((size_t)E * 64);   // [E,128] bf16
    float* e_lg  = alloc((size_t)E2 * 4);                             // raw lg scores
    float* e_g   = alloc((size_t)E * 4);                              // raw -> exp g scores
    unsigned* gmax = (unsigned*)alloc((size_t)N * 4);
    float* gden  = alloc((size_t)N * 4);
    int* row_ptr = (int*)alloc((size_t)E + 4);
    int* colidx  = (int*)alloc((size_t)E2);
    int* cnt     = (int*)alloc((size_t)E);
    int* cursor  = (int*)alloc((size_t)E);
    int* bsum    = (int*)alloc(1024);

    unsigned short* h1 = ni_lg;
    unsigned short* h2 = nj_lg;

    (void)n_in; (void)out_size; (void)ws_size;
    float* outp = (float*)d_out;
    dim3 blk(256);

    hipMemsetAsync(cnt,    0, (size_t)E * 4, stream);
    hipMemsetAsync(cursor, 0, (size_t)E * 4, stream);
    hipMemsetAsync(gmax,   0, (size_t)N * 4 * 4, stream);
    hipMemsetAsync(gden,   0, (size_t)N * 4 * 4, stream);

    // weights -> bf16
    f2bf_k<<<128, blk, 0, stream>>>(W_g_ni,    wgni_bf,    32768);
    f2bf_k<<<128, blk, 0, stream>>>(W_g_nj,    wgnj_bf,    32768);
    f2bf_k<<<128, blk, 0, stream>>>(W_lg_ni,   wlgni_bf,   32768);
    f2bf_k<<<128, blk, 0, stream>>>(W_lg_nj,   wlgnj_bf,   32768);
    f2bf_k<<<128, blk, 0, stream>>>(W_lg_fij,  wlgfij_bf,  32768);
    f2bf_k<<<128, blk, 0, stream>>>(W_g_fij,   wgfij_bf,   32768);
    f2bf_k<<<256, blk, 0, stream>>>(W_lg_node, wlgnode_bf, 65536);
    f2bf_k<<<256, blk, 0, stream>>>(W_g_node,  wgnode_bf,  65536);

    // CSR over lg_dst
    const int nb = (E + 255) / 256;
    count_k<<<(E2 + 255) / 256, blk, 0, stream>>>(lg_dst, cnt, E2);
    scan1<<<nb, blk, 0, stream>>>(cnt, row_ptr, bsum, E);
    scan2<<<1, 1024, 0, stream>>>(bsum, nb);
    scan3<<<nb, blk, 0, stream>>>(row_ptr, bsum, E, E2);
    fill_k<<<(E2 + 255) / 256, blk, 0, stream>>>(lg_dst, row_ptr, cursor, colidx, E2);

    // projection GEMMs (K=128 -> 256 cols, bf16 out)
    gemm128_mfma<<<(N + 63) / 64, blk, 0, stream>>>(l_feats, wgni_bf, nullptr, gni, N);
    gemm128_mfma<<<(N + 63) / 64, blk, 0, stream>>>(l_feats, wgnj_bf, nullptr, gnj, N);
    gemm128_mfma<<<(E + 63) / 64, blk, 0, stream>>>(m_feats, wlgni_bf, nullptr, ni_lg, E);
    gemm128_mfma<<<(E + 63) / 64, blk, 0, stream>>>(m_feats, wlgnj_bf, nullptr, nj_lg, E);

    // fused fij GEMM + raw scores (lg: raw only; g: + segment max)
    gemm_score_mfma<<<(E2 + 63) / 64, blk, 0, stream>>>(
        x_feats, wlgfij_bf, ni_lg, nj_lg, bias_lg, lg_attn, lg_src, lg_dst,
        e_lg, nullptr, E2, 0);
    gemm_score_mfma<<<(E + 63) / 64, blk, 0, stream>>>(
        m_feats, wgfij_bf, gni, gnj, bias_g, g_attn, g_src, g_dst,
        e_g, gmax, E, 1);

    // g softmax pass 2 (exp + denom)
    edge_exp<<<(unsigned)(((long long)E * 4 + 255) / 256), blk, 0, stream>>>(e_g, gmax, gden, g_dst, E);

    // CSR mean-gather of x_feats -> aggbf
    agg_gather<<<(E + 3) / 4, blk, 0, stream>>>(row_ptr, colidx, x_feats, aggbf, E);

    // node-update GEMMs (overwrite ni_lg/nj_lg -> h1/h2; safe after gemm_score)
    gemm256_mfma<<<(E + 63) / 64, blk, 0, stream>>>(
        m_feats, (const void*)aggbf, nullptr, nullptr, wlgnode_bf, b_lg_node, h1, E, 0);
    gemm256_mfma<<<(E + 63) / 64, blk, 0, stream>>>(
        l_feats, (const void*)m_feats, g_src, g_dst, wgnode_bf, b_g_node, h2, E, 1);

    // final: local lg softmax + weighted gathers + epilogue
    final_agg<<<(E + 3) / 4, blk, 0, stream>>>(
        row_ptr, colidx, lg_src, e_lg, h1, h2, e_g, gden, g_dst, outp, E);
}

// Round 5
// 1638.027 us; speedup vs baseline: 48.1777x; 1.0197x over previous
//
#include <hip/hip_runtime.h>
#include <math.h>

#define LRELU(x) ((x) > 0.0f ? (x) : 0.01f * (x))

typedef __attribute__((ext_vector_type(8))) short short8;
typedef __attribute__((ext_vector_type(4))) float f32x4;

__device__ __forceinline__ unsigned fenc(float f) {
    unsigned u = __float_as_uint(f);
    return (u & 0x80000000u) ? ~u : (u | 0x80000000u);
}
__device__ __forceinline__ float fdec(unsigned u) {
    return __uint_as_float((u & 0x80000000u) ? (u & 0x7FFFFFFFu) : ~u);
}
__device__ __forceinline__ unsigned short f2bf(float f) {
    unsigned u = __float_as_uint(f);
    u += 0x7FFFu + ((u >> 16) & 1u);
    return (unsigned short)(u >> 16);
}
__device__ __forceinline__ float bf2f(unsigned short b) {
    return __uint_as_float(((unsigned)b) << 16);
}
__device__ __forceinline__ ushort4 cvt4(float4 v) {
    ushort4 p;
    p.x = f2bf(v.x); p.y = f2bf(v.y); p.z = f2bf(v.z); p.w = f2bf(v.w);
    return p;
}

// ---- fp32 -> bf16 bulk convert (weights) ----
__global__ __launch_bounds__(256) void f2bf_k(
    const float* __restrict__ in, unsigned short* __restrict__ out, int n)
{
    for (int i = blockIdx.x * 256 + threadIdx.x; i < n; i += gridDim.x * 256)
        out[i] = f2bf(in[i]);
}

// ============ MFMA GEMM: C[M,256](bf16) = A[M,128](fp32) @ Wbf[256,128]^T ============
__global__ __launch_bounds__(256) void gemm128_mfma(
    const float* __restrict__ A, const unsigned short* __restrict__ Wbf,
    const float* __restrict__ biasf, unsigned short* __restrict__ Cout, int M)
{
    __shared__ __align__(16) unsigned short smem[64 * 264];
    const int row0 = blockIdx.x * 64;
    const int tid = threadIdx.x;
    const int wv = tid >> 6, lane = tid & 63;
    const int ln = lane & 15, quad = lane >> 4;

#pragma unroll 1
    for (int i = tid; i < 2048; i += 256) {
        int row = i >> 5, c4 = (i & 31) * 4;
        int r = row0 + row;
        float4 v = make_float4(0.f, 0.f, 0.f, 0.f);
        if (r < M) v = *(const float4*)&A[(size_t)r * 128 + c4];
        *(ushort4*)&smem[row * 136 + c4] = cvt4(v);
    }
    __syncthreads();

    f32x4 acc[16];
#pragma unroll
    for (int t = 0; t < 16; ++t) acc[t] = (f32x4){0.f, 0.f, 0.f, 0.f};

#pragma unroll 1
    for (int ks = 0; ks < 4; ++ks) {
        short8 a = *(const short8*)&smem[(wv * 16 + ln) * 136 + ks * 32 + quad * 8];
#pragma unroll
        for (int t = 0; t < 16; ++t) {
            short8 b = *(const short8*)&Wbf[(size_t)(t * 16 + ln) * 128 + ks * 32 + quad * 8];
            acc[t] = __builtin_amdgcn_mfma_f32_16x16x32_bf16(a, b, acc[t], 0, 0, 0);
        }
    }
    __syncthreads();

#pragma unroll
    for (int t = 0; t < 16; ++t) {
        int col = t * 16 + ln;
        float bb = biasf ? biasf[col] : 0.0f;
#pragma unroll
        for (int rg = 0; rg < 4; ++rg)
            smem[(wv * 16 + quad * 4 + rg) * 264 + col] = f2bf(acc[t][rg] + bb);
    }
    __syncthreads();
#pragma unroll 1
    for (int i = tid; i < 2048; i += 256) {
        int row = i >> 5, c8 = (i & 31) * 8;
        int r = row0 + row;
        if (r < M) *(short8*)&Cout[(size_t)r * 256 + c8] = *(const short8*)&smem[row * 264 + c8];
    }
}

// ============ fused fij MFMA GEMM + attention score ============
// Epilogue v2: stash fij C-layout -> row-major bf16 LDS (conflict-free, no barrier
// needed: each wave reads only rows it wrote), then per-row coalesced gathers of
// fni[src]/fnj[dst] + parallel 4-head shuffle reduction (one head per quad).
__global__ __launch_bounds__(256) void gemm_score_mfma(
    const float* __restrict__ A, const unsigned short* __restrict__ Wbf,
    const unsigned short* __restrict__ fni, const unsigned short* __restrict__ fnj,
    const float* __restrict__ bias, const float* __restrict__ attn,
    const int* __restrict__ src, const int* __restrict__ dst,
    float* __restrict__ ebuf, unsigned* __restrict__ smax, int M, int domax)
{
    __shared__ __align__(16) unsigned short smem[64 * 264]; // A-stage [64][136] then fij stash [64][264]
    const int row0 = blockIdx.x * 64;
    const int tid = threadIdx.x;
    const int wv = tid >> 6, lane = tid & 63;
    const int ln = lane & 15, quad = lane >> 4;

#pragma unroll 1
    for (int i = tid; i < 2048; i += 256) {
        int row = i >> 5, c4 = (i & 31) * 4;
        int r = row0 + row;
        float4 v = make_float4(0.f, 0.f, 0.f, 0.f);
        if (r < M) v = *(const float4*)&A[(size_t)r * 128 + c4];
        *(ushort4*)&smem[row * 136 + c4] = cvt4(v);
    }
    __syncthreads();

    f32x4 acc[16];
#pragma unroll
    for (int t = 0; t < 16; ++t) acc[t] = (f32x4){0.f, 0.f, 0.f, 0.f};

#pragma unroll 1
    for (int ks = 0; ks < 4; ++ks) {
        short8 a = *(const short8*)&smem[(wv * 16 + ln) * 136 + ks * 32 + quad * 8];
#pragma unroll
        for (int t = 0; t < 16; ++t) {
            short8 b = *(const short8*)&Wbf[(size_t)(t * 16 + ln) * 128 + ks * 32 + quad * 8];
            acc[t] = __builtin_amdgcn_mfma_f32_16x16x32_bf16(a, b, acc[t], 0, 0, 0);
        }
    }
    __syncthreads();  // all waves done reading A-stage before stash overwrites it

    // stash fij (bf16) row-major; wave wv owns rows [wv*16, wv*16+16)
#pragma unroll
    for (int t = 0; t < 16; ++t) {
        int col = t * 16 + ln;
#pragma unroll
        for (int rg = 0; rg < 4; ++rg)
            smem[(wv * 16 + quad * 4 + rg) * 264 + col] = f2bf(acc[t][rg]);
    }
    // NO barrier: each wave reads only its own rows (intra-wave lgkmcnt ordering)

    const int c4 = lane * 4;                    // this lane's 4 columns
    const float4 bias4 = *(const float4*)&bias[c4];
    const float4 attn4 = *(const float4*)&attn[c4];

#pragma unroll 4
    for (int i = 0; i < 16; ++i) {
        int rr = wv * 16 + i;
        int r = row0 + rr;
        if (r >= M) continue;
        int s = src[r], d = dst[r];
        ushort4 f4 = *(const ushort4*)&smem[rr * 264 + c4];
        ushort4 u4 = *(const ushort4*)&fni[(size_t)s * 256 + c4];
        ushort4 v4 = *(const ushort4*)&fnj[(size_t)d * 256 + c4];
        float p = 0.f;
        {
            float v0 = bf2f(f4.x) + bf2f(u4.x) + bf2f(v4.x) + bias4.x;
            float v1 = bf2f(f4.y) + bf2f(u4.y) + bf2f(v4.y) + bias4.y;
            float v2 = bf2f(f4.z) + bf2f(u4.z) + bf2f(v4.z) + bias4.z;
            float v3 = bf2f(f4.w) + bf2f(u4.w) + bf2f(v4.w) + bias4.w;
            p = LRELU(v0) * attn4.x + LRELU(v1) * attn4.y
              + LRELU(v2) * attn4.z + LRELU(v3) * attn4.w;
        }
        // reduce across the 16 lanes of this quad (head = quad)
        p += __shfl_xor(p, 1, 64);
        p += __shfl_xor(p, 2, 64);
        p += __shfl_xor(p, 4, 64);
        p += __shfl_xor(p, 8, 64);
        if (ln == 0) {
            ebuf[(size_t)r * 4 + quad] = p;
            if (domax) atomicMax(&smax[(size_t)d * 4 + quad], fenc(p));
        }
    }
}

// ============ K=256 MFMA GEMM for h1 (mode 0) / h2 (mode 1), +bias, bf16 out ============
__global__ __launch_bounds__(256) void gemm256_mfma(
    const float* __restrict__ A0, const void* __restrict__ A1v,
    const int* __restrict__ gsrc, const int* __restrict__ gdst,
    const unsigned short* __restrict__ Wbf, const float* __restrict__ biasf,
    unsigned short* __restrict__ Cout, int M, int mode)
{
    __shared__ __align__(16) unsigned short smem[64 * 264];
    const int row0 = blockIdx.x * 64;
    const int tid = threadIdx.x;
    const int wv = tid >> 6, lane = tid & 63;
    const int ln = lane & 15, quad = lane >> 4;

    if (mode == 0) {
        const unsigned short* A1 = (const unsigned short*)A1v;
#pragma unroll 1
        for (int i = tid; i < 2048; i += 256) {
            int row = i >> 5, c4 = (i & 31) * 4;
            int r = row0 + row;
            float4 v = make_float4(0.f, 0.f, 0.f, 0.f);
            if (r < M) v = *(const float4*)&A0[(size_t)r * 128 + c4];
            *(ushort4*)&smem[row * 264 + c4] = cvt4(v);
        }
#pragma unroll 1
        for (int i = tid; i < 1024; i += 256) {
            int row = i >> 4, c8 = (i & 15) * 8;
            int r = row0 + row;
            short8 v;
#pragma unroll
            for (int q = 0; q < 8; ++q) v[q] = 0;
            if (r < M) v = *(const short8*)&A1[(size_t)r * 128 + c8];
            *(short8*)&smem[row * 264 + 128 + c8] = v;
        }
    } else {
        const float* A1 = (const float*)A1v;
#pragma unroll 1
        for (int i = tid; i < 2048; i += 256) {
            int row = i >> 5, c4 = (i & 31) * 4;
            int r = row0 + row;
            float4 v = make_float4(0.f, 0.f, 0.f, 0.f);
            if (r < M) {
                float4 a = *(const float4*)&A0[(size_t)gsrc[r] * 128 + c4];
                float4 b = *(const float4*)&A0[(size_t)gdst[r] * 128 + c4];
                v = make_float4(a.x + b.x, a.y + b.y, a.z + b.z, a.w + b.w);
            }
            *(ushort4*)&smem[row * 264 + c4] = cvt4(v);
        }
#pragma unroll 1
        for (int i = tid; i < 2048; i += 256) {
            int row = i >> 5, c4 = (i & 31) * 4;
            int r = row0 + row;
            float4 v = make_float4(0.f, 0.f, 0.f, 0.f);
            if (r < M) v = *(const float4*)&A1[(size_t)r * 128 + c4];
            *(ushort4*)&smem[row * 264 + 128 + c4] = cvt4(v);
        }
    }
    __syncthreads();

    f32x4 acc[16];
#pragma unroll
    for (int t = 0; t < 16; ++t) acc[t] = (f32x4){0.f, 0.f, 0.f, 0.f};

#pragma unroll 1
    for (int ks = 0; ks < 8; ++ks) {
        short8 a = *(const short8*)&smem[(wv * 16 + ln) * 264 + ks * 32 + quad * 8];
#pragma unroll
        for (int t = 0; t < 16; ++t) {
            short8 b = *(const short8*)&Wbf[(size_t)(t * 16 + ln) * 256 + ks * 32 + quad * 8];
            acc[t] = __builtin_amdgcn_mfma_f32_16x16x32_bf16(a, b, acc[t], 0, 0, 0);
        }
    }
    __syncthreads();

#pragma unroll
    for (int t = 0; t < 16; ++t) {
        int col = t * 16 + ln;
        float bb = biasf[col];
#pragma unroll
        for (int rg = 0; rg < 4; ++rg)
            smem[(wv * 16 + quad * 4 + rg) * 264 + col] = f2bf(acc[t][rg] + bb);
    }
    __syncthreads();
#pragma unroll 1
    for (int i = tid; i < 2048; i += 256) {
        int row = i >> 5, c8 = (i & 31) * 8;
        int r = row0 + row;
        if (r < M) *(short8*)&Cout[(size_t)r * 256 + c8] = *(const short8*)&smem[row * 264 + c8];
    }
}

// ---------------- softmax pass 2 (g branch): exp(e-max), atomic denom ----------------
__global__ __launch_bounds__(256) void edge_exp(
    float* __restrict__ ebuf, const unsigned* __restrict__ smax,
    float* __restrict__ sden, const int* __restrict__ dst, int nE)
{
    int i = blockIdx.x * 256 + threadIdx.x;
    if (i >= nE * 4) return;
    int e = i >> 2, h = i & 3;
    int d = dst[e];
    float m = fdec(smax[(size_t)d * 4 + h]);
    float ex = expf(ebuf[i] - m);
    ebuf[i] = ex;
    atomicAdd(&sden[(size_t)d * 4 + h], ex);
}

// ================= CSR build over lg_dst =================
__global__ __launch_bounds__(256) void count_k(
    const int* __restrict__ dst, int* __restrict__ cnt, int n)
{
    int i = blockIdx.x * 256 + threadIdx.x;
    if (i < n) atomicAdd(&cnt[dst[i]], 1);
}

__global__ __launch_bounds__(256) void scan1(
    const int* __restrict__ cnt, int* __restrict__ excl, int* __restrict__ bsum, int n)
{
    __shared__ int sd[256];
    int tid = threadIdx.x;
    int i = blockIdx.x * 256 + tid;
    int v = (i < n) ? cnt[i] : 0;
    sd[tid] = v;
    __syncthreads();
    for (int off2 = 1; off2 < 256; off2 <<= 1) {
        int t = (tid >= off2) ? sd[tid - off2] : 0;
        __syncthreads();
        sd[tid] += t;
        __syncthreads();
    }
    if (i < n) excl[i] = sd[tid] - v;
    if (tid == 255) bsum[blockIdx.x] = sd[255];
}

__global__ __launch_bounds__(1024) void scan2(int* __restrict__ bsum, int nb)
{
    __shared__ int sd[1024];
    int tid = threadIdx.x;
    int v = (tid < nb) ? bsum[tid] : 0;
    sd[tid] = v;
    __syncthreads();
    for (int off2 = 1; off2 < 1024; off2 <<= 1) {
        int t = (tid >= off2) ? sd[tid - off2] : 0;
        __syncthreads();
        sd[tid] += t;
        __syncthreads();
    }
    if (tid < nb) bsum[tid] = sd[tid] - v;  // exclusive
}

__global__ __launch_bounds__(256) void scan3(
    int* __restrict__ excl, const int* __restrict__ bsum, int n, int total)
{
    int i = blockIdx.x * 256 + threadIdx.x;
    if (i < n) excl[i] += bsum[i >> 8];
    if (i == 0) excl[n] = total;
}

__global__ __launch_bounds__(256) void fill_k(
    const int* __restrict__ dst, const int* __restrict__ row_ptr,
    int* __restrict__ cursor, int* __restrict__ colidx, int n)
{
    int i = blockIdx.x * 256 + threadIdx.x;
    if (i >= n) return;
    int d = dst[i];
    int p = atomicAdd(&cursor[d], 1);
    colidx[row_ptr[d] + p] = i;
}

// ---------------- CSR mean-gather of x_feats onto lg_dst (bf16 out) ----------------
__global__ __launch_bounds__(256) void agg_gather(
    const int* __restrict__ row_ptr, const int* __restrict__ colidx,
    const float* __restrict__ x, unsigned short* __restrict__ aggbf, int nE)
{
    const int lane = threadIdx.x & 63;
    const int d = blockIdx.x * 4 + (threadIdx.x >> 6);
    if (d >= nE) return;
    int b = row_ptr[d], en = row_ptr[d + 1];
    float s0 = 0.f, s1 = 0.f;
    for (int k = b; k < en; ++k) {
        int e = colidx[k];
        float2 v = *(const float2*)&x[(size_t)e * 128 + lane * 2];
        s0 += v.x; s1 += v.y;
    }
    float c = fmaxf((float)(en - b), 1.0f);
    ushort2 o;
    o.x = f2bf(s0 / c); o.y = f2bf(s1 / c);
    *(ushort2*)&aggbf[(size_t)d * 128 + lane * 2] = o;
}

// ---------------- final: local lg-softmax + weighted gather + epilogue ----------------
__global__ __launch_bounds__(256) void final_agg(
    const int* __restrict__ row_ptr, const int* __restrict__ colidx,
    const int* __restrict__ lg_src, const float* __restrict__ e_lg,
    const unsigned short* __restrict__ h1, const unsigned short* __restrict__ h2,
    const float* __restrict__ e_g, const float* __restrict__ gden,
    const int* __restrict__ g_dst, float* __restrict__ out, int nE)
{
    const int lane = threadIdx.x & 63;
    const int d = blockIdx.x * 4 + (threadIdx.x >> 6);
    if (d >= nE) return;
    int b = row_ptr[d], en = row_ptr[d + 1];

    float mx0 = -1e30f, mx1 = -1e30f, mx2 = -1e30f, mx3 = -1e30f;
    for (int k = b; k < en; ++k) {
        float4 sc = *(const float4*)&e_lg[(size_t)colidx[k] * 4];
        mx0 = fmaxf(mx0, sc.x); mx1 = fmaxf(mx1, sc.y);
        mx2 = fmaxf(mx2, sc.z); mx3 = fmaxf(mx3, sc.w);
    }
    float den0 = 0.f, den1 = 0.f, den2 = 0.f, den3 = 0.f;
    float a10 = 0.f, a11 = 0.f, a12 = 0.f, a13 = 0.f;
    float a20 = 0.f, a21 = 0.f, a22 = 0.f, a23 = 0.f;
    for (int k = b; k < en; ++k) {
        int e = colidx[k];
        float4 sc = *(const float4*)&e_lg[(size_t)e * 4];
        float w0 = expf(sc.x - mx0), w1 = expf(sc.y - mx1);
        float w2 = expf(sc.z - mx2), w3 = expf(sc.w - mx3);
        den0 += w0; den1 += w1; den2 += w2; den3 += w3;
        int s = lg_src[e];
        const unsigned short* p1 = &h1[(size_t)s * 256 + lane];
        const unsigned short* p2 = &h2[(size_t)s * 256 + lane];
        a10 += bf2f(p1[0])   * w0;
        a11 += bf2f(p1[64])  * w1;
        a12 += bf2f(p1[128]) * w2;
        a13 += bf2f(p1[192]) * w3;
        a20 += bf2f(p2[0]);
        a21 += bf2f(p2[64]);
        a22 += bf2f(p2[128]);
        a23 += bf2f(p2[192]);
    }
    float o = 0.f;
    if (en > b) {
        float v0 = a10 / den0, v1 = a11 / den1, v2 = a12 / den2, v3 = a13 / den3;
        o += LRELU(v0) + LRELU(v1) + LRELU(v2) + LRELU(v3);
    }
    int gd = g_dst[d];
    float g0 = e_g[(size_t)d * 4 + 0] / gden[(size_t)gd * 4 + 0] * a20;
    float g1 = e_g[(size_t)d * 4 + 1] / gden[(size_t)gd * 4 + 1] * a21;
    float g2 = e_g[(size_t)d * 4 + 2] / gden[(size_t)gd * 4 + 2] * a22;
    float g3 = e_g[(size_t)d * 4 + 3] / gden[(size_t)gd * 4 + 3] * a23;
    o += LRELU(g0) + LRELU(g1) + LRELU(g2) + LRELU(g3);
    out[(size_t)d * 64 + lane] = o;
}

extern "C" void kernel_launch(void* const* d_in, const int* in_sizes, int n_in,
                              void* d_out, int out_size, void* d_ws, size_t ws_size,
                              hipStream_t stream)
{
    const float* l_feats   = (const float*)d_in[0];
    const float* m_feats   = (const float*)d_in[1];
    const float* x_feats   = (const float*)d_in[2];
    const int*   g_src     = (const int*)d_in[3];
    const int*   g_dst     = (const int*)d_in[4];
    const int*   lg_src    = (const int*)d_in[5];
    const int*   lg_dst    = (const int*)d_in[6];
    const float* W_lg_node = (const float*)d_in[7];
    const float* b_lg_node = (const float*)d_in[8];
    const float* W_lg_ni   = (const float*)d_in[9];
    const float* W_lg_fij  = (const float*)d_in[10];
    const float* W_lg_nj   = (const float*)d_in[11];
    const float* lg_attn   = (const float*)d_in[12];
    const float* bias_lg   = (const float*)d_in[13];
    const float* W_g_node  = (const float*)d_in[14];
    const float* b_g_node  = (const float*)d_in[15];
    const float* W_g_ni    = (const float*)d_in[16];
    const float* W_g_fij   = (const float*)d_in[17];
    const float* W_g_nj    = (const float*)d_in[18];
    const float* g_attn    = (const float*)d_in[19];
    const float* bias_g    = (const float*)d_in[20];

    const int N  = in_sizes[0] / 128;
    const int E  = in_sizes[3];
    const int E2 = in_sizes[5];

    float* ws = (float*)d_ws;
    size_t off = 0;
    auto alloc = [&](size_t n) { float* p = ws + off; off += n; return p; };

    // bf16 weights (ushort offsets within a float-slot arena)
    unsigned short* wbuf = (unsigned short*)alloc(163840);
    unsigned short* wgni_bf    = wbuf;
    unsigned short* wgnj_bf    = wbuf + 32768;
    unsigned short* wlgni_bf   = wbuf + 65536;
    unsigned short* wlgnj_bf   = wbuf + 98304;
    unsigned short* wlgfij_bf  = wbuf + 131072;
    unsigned short* wgfij_bf   = wbuf + 163840;
    unsigned short* wlgnode_bf = wbuf + 196608;
    unsigned short* wgnode_bf  = wbuf + 262144;

    unsigned short* ni_lg = (unsigned short*)alloc((size_t)E * 128);  // [E,256] bf16 -> h1
    unsigned short* nj_lg = (unsigned short*)alloc((size_t)E * 128);  // [E,256] bf16 -> h2
    unsigned short* gni   = (unsigned short*)alloc((size_t)N * 128);
    unsigned short* gnj   = (unsigned short*)alloc((size_t)N * 128);
    unsigned short* aggbf = (unsigned short*)alloc((size_t)E * 64);   // [E,128] bf16
    float* e_lg  = alloc((size_t)E2 * 4);                             // raw lg scores
    float* e_g   = alloc((size_t)E * 4);                              // raw -> exp g scores
    unsigned* gmax = (unsigned*)alloc((size_t)N * 4);
    float* gden  = alloc((size_t)N * 4);
    int* row_ptr = (int*)alloc((size_t)E + 4);
    int* colidx  = (int*)alloc((size_t)E2);
    int* cnt     = (int*)alloc((size_t)E);
    int* cursor  = (int*)alloc((size_t)E);
    int* bsum    = (int*)alloc(1024);

    unsigned short* h1 = ni_lg;
    unsigned short* h2 = nj_lg;

    (void)n_in; (void)out_size; (void)ws_size;
    float* outp = (float*)d_out;
    dim3 blk(256);

    hipMemsetAsync(cnt,    0, (size_t)E * 4, stream);
    hipMemsetAsync(cursor, 0, (size_t)E * 4, stream);
    hipMemsetAsync(gmax,   0, (size_t)N * 4 * 4, stream);
    hipMemsetAsync(gden,   0, (size_t)N * 4 * 4, stream);

    // weights -> bf16
    f2bf_k<<<128, blk, 0, stream>>>(W_g_ni,    wgni_bf,    32768);
    f2bf_k<<<128, blk, 0, stream>>>(W_g_nj,    wgnj_bf,    32768);
    f2bf_k<<<128, blk, 0, stream>>>(W_lg_ni,   wlgni_bf,   32768);
    f2bf_k<<<128, blk, 0, stream>>>(W_lg_nj,   wlgnj_bf,   32768);
    f2bf_k<<<128, blk, 0, stream>>>(W_lg_fij,  wlgfij_bf,  32768);
    f2bf_k<<<128, blk, 0, stream>>>(W_g_fij,   wgfij_bf,   32768);
    f2bf_k<<<256, blk, 0, stream>>>(W_lg_node, wlgnode_bf, 65536);
    f2bf_k<<<256, blk, 0, stream>>>(W_g_node,  wgnode_bf,  65536);

    // CSR over lg_dst
    const int nb = (E + 255) / 256;
    count_k<<<(E2 + 255) / 256, blk, 0, stream>>>(lg_dst, cnt, E2);
    scan1<<<nb, blk, 0, stream>>>(cnt, row_ptr, bsum, E);
    scan2<<<1, 1024, 0, stream>>>(bsum, nb);
    scan3<<<nb, blk, 0, stream>>>(row_ptr, bsum, E, E2);
    fill_k<<<(E2 + 255) / 256, blk, 0, stream>>>(lg_dst, row_ptr, cursor, colidx, E2);

    // projection GEMMs (K=128 -> 256 cols, bf16 out)
    gemm128_mfma<<<(N + 63) / 64, blk, 0, stream>>>(l_feats, wgni_bf, nullptr, gni, N);
    gemm128_mfma<<<(N + 63) / 64, blk, 0, stream>>>(l_feats, wgnj_bf, nullptr, gnj, N);
    gemm128_mfma<<<(E + 63) / 64, blk, 0, stream>>>(m_feats, wlgni_bf, nullptr, ni_lg, E);
    gemm128_mfma<<<(E + 63) / 64, blk, 0, stream>>>(m_feats, wlgnj_bf, nullptr, nj_lg, E);

    // fused fij GEMM + raw scores (lg: raw only; g: + segment max)
    gemm_score_mfma<<<(E2 + 63) / 64, blk, 0, stream>>>(
        x_feats, wlgfij_bf, ni_lg, nj_lg, bias_lg, lg_attn, lg_src, lg_dst,
        e_lg, nullptr, E2, 0);
    gemm_score_mfma<<<(E + 63) / 64, blk, 0, stream>>>(
        m_feats, wgfij_bf, gni, gnj, bias_g, g_attn, g_src, g_dst,
        e_g, gmax, E, 1);

    // g softmax pass 2 (exp + denom)
    edge_exp<<<(unsigned)(((long long)E * 4 + 255) / 256), blk, 0, stream>>>(e_g, gmax, gden, g_dst, E);

    // CSR mean-gather of x_feats -> aggbf
    agg_gather<<<(E + 3) / 4, blk, 0, stream>>>(row_ptr, colidx, x_feats, aggbf, E);

    // node-update GEMMs (overwrite ni_lg/nj_lg -> h1/h2; safe after gemm_score)
    gemm256_mfma<<<(E + 63) / 64, blk, 0, stream>>>(
        m_feats, (const void*)aggbf, nullptr, nullptr, wlgnode_bf, b_lg_node, h1, E, 0);
    gemm256_mfma<<<(E + 63) / 64, blk, 0, stream>>>(
        l_feats, (const void*)m_feats, g_src, g_dst, wgnode_bf, b_g_node, h2, E, 1);

    // final: local lg softmax + weighted gathers + epilogue
    final_agg<<<(E + 3) / 4, blk, 0, stream>>>(
        row_ptr, colidx, lg_src, e_lg, h1, h2, e_g, gden, g_dst, outp, E);
}